// Round 1
// baseline (236.899 us; speedup 1.0000x reference)
//
#include <hip/hip_runtime.h>
#include <hip/hip_fp16.h>
#include <math.h>

#define N_NODES 10000
#define E_EDGES 160000
#define DMODEL 64
#define H 4
#define NBOUND 31
#define SLOTS 64  // fixed per-node CSR bucket; P(deg>64)<1e-11 for multinomial(16)
// qall record per node (fp16, 1024 halves):
//  [0:256)    h  d-major: offset d*4 + head   (one 8B load = all 4 heads at d)
//  [256:512)  q1: 256 + head*64 + d
//  [512:768)  q2: 512 + head*64 + d
//  [768:1024) q3: 768 + head*64 + d
#define QREC 1024

typedef _Float16 half8 __attribute__((ext_vector_type(8)));
typedef float floatx4 __attribute__((ext_vector_type(4)));

// ---------------------------------------------------------------------------
// LDS 64-wide microtile helper: o[r] = sum_t A[i0+r][t] * B[t][j].
// ---------------------------------------------------------------------------
__device__ __forceinline__ void mm4(const float* __restrict__ S, int aoff,
                                    int astride, int boff, int i0, int j,
                                    int Kdim, float o[4]) {
  float a0 = 0.f, a1 = 0.f, a2 = 0.f, a3 = 0.f;
  for (int t4 = 0; t4 < (Kdim >> 2); ++t4) {
    float4 f0 = *(const float4*)&S[aoff + (i0 + 0) * astride + t4 * 4];
    float4 f1 = *(const float4*)&S[aoff + (i0 + 1) * astride + t4 * 4];
    float4 f2 = *(const float4*)&S[aoff + (i0 + 2) * astride + t4 * 4];
    float4 f3 = *(const float4*)&S[aoff + (i0 + 3) * astride + t4 * 4];
    float b0 = S[boff + (t4 * 4 + 0) * 64 + j];
    float b1 = S[boff + (t4 * 4 + 1) * 64 + j];
    float b2 = S[boff + (t4 * 4 + 2) * 64 + j];
    float b3 = S[boff + (t4 * 4 + 3) * 64 + j];
    a0 += f0.x * b0 + f0.y * b1 + f0.z * b2 + f0.w * b3;
    a1 += f1.x * b0 + f1.y * b1 + f1.z * b2 + f1.w * b3;
    a2 += f2.x * b0 + f2.y * b1 + f2.z * b2 + f2.w * b3;
    a3 += f3.x * b0 + f3.y * b1 + f3.z * b2 + f3.w * b3;
  }
  o[0] = a0; o[1] = a1; o[2] = a2; o[3] = a3;
}

__device__ __forceinline__ int didx(const float* __restrict__ bnd2, float d) {
  int g = (int)(d * 10.0f);
  g = (g < 0) ? 0 : ((g > 31) ? 31 : g);
  g += (bnd2[g + 1] < d) ? 1 : 0;
  g -= (bnd2[g] >= d) ? 1 : 0;
  return g;
}

// ---------------------------------------------------------------------------
// D1: blocks 0..11   = full per-(k,h) precompute (B1->WC->B2->GB->U)
//     blocks 12..636 = edge pass: dist->bucket index, CSR scatter of packed
//                      16B edge record into ebuf[t*SLOTS + atomicAdd(cnt[t])].
// record uint4: x = s | it0<<16 ; y = it1 | it2<<16 ;
//               z = it3 | i1<<16 | q2_0<<21 | q__0<<26 ;
//               w = (q2_h | q__h<<5) << ((h-1)*10)  for h=1..3
// ---------------------------------------------------------------------------
__global__ __launch_bounds__(256) void prep_kernel(
    const float* __restrict__ fc1, const float* __restrict__ fc2,
    const float* __restrict__ fc3, const float* __restrict__ fcc,
    const float* __restrict__ Wfc, const float* __restrict__ G,
    const float* __restrict__ emb, const float* __restrict__ pos,
    const int* __restrict__ src, const int* __restrict__ dst,
    const int* __restrict__ inter, const float* __restrict__ boundaries,
    __half* __restrict__ bigWT, __half* __restrict__ U16,
    int* __restrict__ cnt, uint4* __restrict__ ebuf) {
  __shared__ __align__(16) float S[12288];
  int bi = blockIdx.x;
  int tid = threadIdx.x;
  if (bi >= 12) {
    // ---- edge pass: dist + bucket scatter ----
    if (tid < NBOUND) S[tid + 1] = boundaries[tid];
    if (tid == NBOUND) { S[0] = -INFINITY; S[32] = INFINITY; }
    __syncthreads();
    int e = (bi - 12) * 256 + tid;  // 625*256 == E exactly
    int s = src[e], t = dst[e];
    int4 iv = *(const int4*)&inter[e * 4];
    int itarr[4] = {iv.x, iv.y, iv.z, iv.w};
    float sx = pos[s * 3], sy = pos[s * 3 + 1], sz = pos[s * 3 + 2];
    float tx = pos[t * 3], ty = pos[t * 3 + 1], tz = pos[t * 3 + 2];
    float dx = tx - sx, dy = ty - sy, dz = tz - sz;
    float dist1 = sqrtf(dx * dx + dy * dy + dz * dz);
    unsigned i1 = (unsigned)didx(S, dist1);
    unsigned w3 = 0, q20 = 0, q_0 = 0;
    #pragma unroll
    for (int h = 0; h < 4; ++h) {
      int it = itarr[h];
      float ix = pos[it * 3], iy = pos[it * 3 + 1], iz = pos[it * 3 + 2];
      float ax = tx - ix, ay = ty - iy, az = tz - iz;
      float dist2 = sqrtf(ax * ax + ay * ay + az * az);
      float bx = sx - ix, by = sy - iy, bz = sz - iz;
      float dist_ = sqrtf(bx * bx + by * by + bz * bz);
      unsigned idx2 = (unsigned)didx(S, dist2);
      unsigned idx_ = (unsigned)didx(S, dist_);
      if (h == 0) { q20 = idx2; q_0 = idx_; }
      else w3 |= (idx2 | (idx_ << 5)) << ((h - 1) * 10);
    }
    uint4 rec;
    rec.x = (unsigned)s | ((unsigned)itarr[0] << 16);
    rec.y = (unsigned)itarr[1] | ((unsigned)itarr[2] << 16);
    rec.z = (unsigned)itarr[3] | (i1 << 16) | (q20 << 21) | (q_0 << 26);
    rec.w = w3;
    int p = atomicAdd(&cnt[t], 1);
    if (p < SLOTS) ebuf[t * SLOTS + p] = rec;
    return;
  }
  // ---- fat precompute path: one block per (k,h) ----
  int k = bi >> 2, h = bi & 3;
  const float* fck = (k == 0) ? fc1 : (k == 1) ? fc2 : fc3;
  fck += h * 128 * 64;
  const float* F = fcc + h * 192 * 64 + k * 64 * 64;
  int j = tid & 63, ig = tid >> 6;
  float o[4];
  // stage F -> S[0:4096), fckU -> S[4096:8192)
  #pragma unroll
  for (int u = 0; u < 4; ++u) {
    ((float4*)S)[u * 256 + tid] = ((const float4*)F)[u * 256 + tid];
    ((float4*)(S + 4096))[u * 256 + tid] = ((const float4*)fck)[u * 256 + tid];
  }
  __syncthreads();
  // B1 = fckU @ F -> S[8192)
  #pragma unroll
  for (int rg = 0; rg < 4; ++rg) {
    int i0 = ig * 16 + rg * 4;
    mm4(S, 4096, 64, 0, i0, j, 64, o);
    S[8192 + (i0 + 0) * 64 + j] = o[0];
    S[8192 + (i0 + 1) * 64 + j] = o[1];
    S[8192 + (i0 + 2) * 64 + j] = o[2];
    S[8192 + (i0 + 3) * 64 + j] = o[3];
  }
  __syncthreads();
  // stage WfcU (rows 0..63, col slice h) -> S[4096)
  #pragma unroll
  for (int u = 0; u < 4; ++u) {
    int fi = u * 256 + tid;
    int i = fi >> 4, c4 = fi & 15;
    ((float4*)(S + 4096))[fi] = ((const float4*)(Wfc + i * 256 + h * 64))[c4];
  }
  __syncthreads();
  if (k == 0) {
    #pragma unroll
    for (int u = 0; u < 16; ++u) {
      int idx = u * 256 + tid;
      int i = idx >> 6, jj = idx & 63;
      bigWT[(h * 64 + jj) * 128 + i] = __float2half(S[4096 + idx]);
    }
  }
  // WC0 = WfcU @ B1 -> bigWT cols 0..63
  #pragma unroll
  for (int rg = 0; rg < 4; ++rg) {
    int i0 = ig * 16 + rg * 4;
    mm4(S, 4096, 64, 8192, i0, j, 64, o);
    int rb = ((k + 1) * 256 + h * 64 + j) * 128;
    bigWT[rb + i0 + 0] = __float2half(o[0]);
    bigWT[rb + i0 + 1] = __float2half(o[1]);
    bigWT[rb + i0 + 2] = __float2half(o[2]);
    bigWT[rb + i0 + 3] = __float2half(o[3]);
  }
  __syncthreads();
  // stage WfcL (rows 64..127) -> S[4096)
  #pragma unroll
  for (int u = 0; u < 4; ++u) {
    int fi = u * 256 + tid;
    int i = fi >> 4, c4 = fi & 15;
    ((float4*)(S + 4096))[fi] =
        ((const float4*)(Wfc + (64 + i) * 256 + h * 64))[c4];
  }
  __syncthreads();
  if (k == 0) {
    #pragma unroll
    for (int u = 0; u < 16; ++u) {
      int idx = u * 256 + tid;
      int i = idx >> 6, jj = idx & 63;
      bigWT[(h * 64 + jj) * 128 + 64 + i] = __float2half(S[4096 + idx]);
    }
  }
  // WC1 = WfcL @ B1 -> bigWT cols 64..127
  #pragma unroll
  for (int rg = 0; rg < 4; ++rg) {
    int i0 = ig * 16 + rg * 4;
    mm4(S, 4096, 64, 8192, i0, j, 64, o);
    int rb = ((k + 1) * 256 + h * 64 + j) * 128;
    bigWT[rb + 64 + i0 + 0] = __float2half(o[0]);
    bigWT[rb + 64 + i0 + 1] = __float2half(o[1]);
    bigWT[rb + 64 + i0 + 2] = __float2half(o[2]);
    bigWT[rb + 64 + i0 + 3] = __float2half(o[3]);
  }
  __syncthreads();
  // stage fckL (rows 64..127) -> S[4096)
  #pragma unroll
  for (int u = 0; u < 4; ++u)
    ((float4*)(S + 4096))[u * 256 + tid] =
        ((const float4*)(fck + 4096))[u * 256 + tid];
  __syncthreads();
  // B2 = fckL @ F -> S[8192)
  #pragma unroll
  for (int rg = 0; rg < 4; ++rg) {
    int i0 = ig * 16 + rg * 4;
    mm4(S, 4096, 64, 0, i0, j, 64, o);
    S[8192 + (i0 + 0) * 64 + j] = o[0];
    S[8192 + (i0 + 1) * 64 + j] = o[1];
    S[8192 + (i0 + 2) * 64 + j] = o[2];
    S[8192 + (i0 + 3) * 64 + j] = o[3];
  }
  __syncthreads();
  // stage G_h -> S[0:2048), emb -> S[2048:3072)
  #pragma unroll
  for (int u = 0; u < 2; ++u)
    ((float4*)S)[u * 256 + tid] = ((const float4*)(G + h * 2048))[u * 256 + tid];
  ((float4*)(S + 2048))[tid] = ((const float4*)emb)[tid];
  __syncthreads();
  // GB = G @ B2 (32x64) -> S[3072)
  #pragma unroll
  for (int rg = 0; rg < 2; ++rg) {
    int i0 = ig * 8 + rg * 4;
    mm4(S, 0, 64, 8192, i0, j, 64, o);
    S[3072 + (i0 + 0) * 64 + j] = o[0];
    S[3072 + (i0 + 1) * 64 + j] = o[1];
    S[3072 + (i0 + 2) * 64 + j] = o[2];
    S[3072 + (i0 + 3) * 64 + j] = o[3];
  }
  __syncthreads();
  // U = emb @ GB (32x64, K=32) -> U16
  #pragma unroll
  for (int rg = 0; rg < 2; ++rg) {
    int i0 = ig * 8 + rg * 4;
    mm4(S, 2048, 32, 3072, i0, j, 32, o);
    int base = k * 8192 + h * 2048;
    U16[base + (i0 + 0) * 64 + j] = __float2half(o[0]);
    U16[base + (i0 + 1) * 64 + j] = __float2half(o[1]);
    U16[base + (i0 + 2) * 64 + j] = __float2half(o[2]);
    U16[base + (i0 + 3) * 64 + j] = __float2half(o[3]);
  }
}

// ---------------------------------------------------------------------------
// D2: MFMA gemm (64 x 256 region tiles, LDS-staged epilogue). A-fragments
// read feat fp32 directly and convert in-register (feat16 pass eliminated).
// ---------------------------------------------------------------------------
#define EROW 264  // epilogue LDS row stride in halves

__global__ __launch_bounds__(256) void gemm_kernel(
    const float* __restrict__ feat, const __half* __restrict__ bigWT,
    __half* __restrict__ qall) {
  __shared__ __align__(16) __half Esm[4][16][EROW];
  int bi = blockIdx.x;
  int tid = threadIdx.x;
  int bx = bi % 157, by = bi / 157;  // by = region 0..3
  int wv = tid >> 6, l = tid & 63;
  int m0 = bx * 64 + wv * 16;
  int n0 = by * 256;
  int lm = l & 15, lk = (l >> 4) * 8;
  int arow = m0 + lm;
  if (arow >= N_NODES) arow = N_NODES - 1;
  const float* fp = feat + arow * 128 + lk;
  const _Float16* bp = (const _Float16*)bigWT + lk;
  half8 a[4];
  #pragma unroll
  for (int kt = 0; kt < 4; ++kt) {
    float4 u0 = *(const float4*)(fp + kt * 32);
    float4 u1 = *(const float4*)(fp + kt * 32 + 4);
    half8 t;
    t[0] = (_Float16)u0.x; t[1] = (_Float16)u0.y;
    t[2] = (_Float16)u0.z; t[3] = (_Float16)u0.w;
    t[4] = (_Float16)u1.x; t[5] = (_Float16)u1.y;
    t[6] = (_Float16)u1.z; t[7] = (_Float16)u1.w;
    a[kt] = t;
  }
  #pragma unroll
  for (int nt = 0; nt < 16; ++nt) {
    floatx4 acc = (floatx4){0.f, 0.f, 0.f, 0.f};
    #pragma unroll
    for (int kt = 0; kt < 4; ++kt) {
      half8 b = *(const half8*)(bp + (n0 + nt * 16 + lm) * 128 + kt * 32);
      acc = __builtin_amdgcn_mfma_f32_16x16x32_f16(a[kt], b, acc, 0, 0, 0);
    }
    int dd = nt * 16 + lm;  // col within region, 0..255
    int o = (by == 0) ? ((dd & 63) * 4 + (dd >> 6)) : dd;
    #pragma unroll
    for (int r4 = 0; r4 < 4; ++r4)
      Esm[wv][(l >> 4) * 4 + r4][o] = __float2half(acc[r4]);
  }
  __syncthreads();
  int row = l >> 2;       // 0..15
  int j0 = (l & 3) * 64;  // 0,64,128,192
  int m = m0 + row;
  if (m < N_NODES) {
    #pragma unroll
    for (int u = 0; u < 8; ++u) {
      uint4 v = *(const uint4*)&Esm[wv][row][j0 + u * 8];
      *(uint4*)&qall[m * QREC + by * 256 + j0 + u * 8] = v;
    }
  }
}

// ---------------------------------------------------------------------------
// D3: FUSED score + aggregation. One block per dst node; 4 waves stride the
// node's CSR bucket, one edge per wave per iter. q3[dst] loaded ONCE per
// block; score lanes = (h,c) layout; agg lanes = d layout reading the same
// freshly-fetched src record. Max-free softmax (|score| <= ~15).
// ---------------------------------------------------------------------------
__device__ __forceinline__ float dpp_row_sum16(float v) {
  int x;
  x = __builtin_amdgcn_update_dpp(0, __float_as_int(v), 0x128, 0xf, 0xf, true);
  v += __int_as_float(x);
  x = __builtin_amdgcn_update_dpp(0, __float_as_int(v), 0x124, 0xf, 0xf, true);
  v += __int_as_float(x);
  x = __builtin_amdgcn_update_dpp(0, __float_as_int(v), 0x122, 0xf, 0xf, true);
  v += __int_as_float(x);
  x = __builtin_amdgcn_update_dpp(0, __float_as_int(v), 0x121, 0xf, 0xf, true);
  v += __int_as_float(x);
  return v;
}

union H4u { uint2 u; __half2 h[2]; };

__device__ __forceinline__ float tanh_dot(H4u A, H4u B, H4u C, H4u X, H4u Y,
                                          H4u Z, float4 a4) {
  __half2 z0 = __hadd2(__hadd2(A.h[0], B.h[0]), __hadd2(C.h[0], X.h[0]));
  z0 = __hadd2(z0, __hadd2(Y.h[0], Z.h[0]));
  __half2 z1 = __hadd2(__hadd2(A.h[1], B.h[1]), __hadd2(C.h[1], X.h[1]));
  z1 = __hadd2(z1, __hadd2(Y.h[1], Z.h[1]));
  float2 f0 = __half22float2(z0);
  float2 f1 = __half22float2(z1);
  const float K = 2.885390082f;  // 2*log2(e)
  float p0 = __builtin_amdgcn_exp2f(f0.x * K);
  float p1 = __builtin_amdgcn_exp2f(f0.y * K);
  float p2 = __builtin_amdgcn_exp2f(f1.x * K);
  float p3 = __builtin_amdgcn_exp2f(f1.y * K);
  float r0 = __builtin_amdgcn_rcpf(p0 + 1.0f);
  float r1 = __builtin_amdgcn_rcpf(p1 + 1.0f);
  float r2 = __builtin_amdgcn_rcpf(p2 + 1.0f);
  float r3 = __builtin_amdgcn_rcpf(p3 + 1.0f);
  float dot = a4.x * r0;
  dot = fmaf(a4.y, r1, dot);
  dot = fmaf(a4.z, r2, dot);
  dot = fmaf(a4.w, r3, dot);
  float asum = (a4.x + a4.y) + (a4.z + a4.w);
  return fmaf(-2.0f, dot, asum);
}

__device__ __forceinline__ float4 h4_to_f4(uint2 u) {
  union { uint2 ui; __half2 h[2]; } cc;
  cc.ui = u;
  float2 a = __half22float2(cc.h[0]);
  float2 b = __half22float2(cc.h[1]);
  return make_float4(a.x, a.y, b.x, b.y);
}

__global__ __launch_bounds__(256) void score_agg_kernel(
    const int* __restrict__ cnt, const uint4* __restrict__ ebuf,
    const __half* __restrict__ qall, const __half* __restrict__ U16,
    const float* __restrict__ aout, float* __restrict__ out) {
  __shared__ uint4 recs[SLOTS];
  __shared__ float4 sm_num[4][64];
  __shared__ float4 sm_den[4];
  int tid = threadIdx.x;
  int w = tid >> 6, lane = tid & 63;
  int h = lane >> 4, c = lane & 15;
  int n = blockIdx.x;
  int deg = cnt[n];
  if (deg > SLOTS) deg = SLOTS;
  // stage the node's edge records into LDS (breaks per-iter latency chain)
  if (tid < deg) recs[tid] = ebuf[n * SLOTS + tid];
  // per-block invariants: q3[dst] fragment + attn_out column
  H4u C;
  C.u = *(const uint2*)(qall + n * QREC + 768 + h * 64 + c * 4);
  const float4 a4 = *((const float4*)(aout + h * 64) + c);
  __syncthreads();
  float4 num = make_float4(0.f, 0.f, 0.f, 0.f);
  float4 den = make_float4(0.f, 0.f, 0.f, 0.f);
  for (int i = w; i < deg; i += 4) {
    uint4 r = recs[i];
    int s = r.x & 0xffff;
    int it = (h == 0) ? (int)(r.x >> 16)
           : (h == 1) ? (int)(r.y & 0xffff)
           : (h == 2) ? (int)(r.y >> 16) : (int)(r.z & 0xffff);
    unsigned i1 = (r.z >> 16) & 31;
    unsigned q2h, q_h;
    if (h == 0) {
      q2h = (r.z >> 21) & 31;
      q_h = (r.z >> 26) & 31;
    } else {
      unsigned f = r.w >> ((h - 1) * 10);
      q2h = f & 31;
      q_h = (f >> 5) & 31;
    }
    H4u A, B, X, Y, Z;
    A.u = *(const uint2*)(qall + s * QREC + 256 + h * 64 + c * 4);
    B.u = *(const uint2*)(qall + it * QREC + 512 + h * 64 + c * 4);
    X.u = *(const uint2*)(U16 + (h * 32 + i1) * 64 + c * 4);
    Y.u = *(const uint2*)(U16 + 8192 + (h * 32 + q2h) * 64 + c * 4);
    Z.u = *(const uint2*)(U16 + 16384 + (h * 32 + q_h) * 64 + c * 4);
    uint2 hr = *(const uint2*)(qall + s * QREC + lane * 4);  // h[d=lane][4 heads]
    float v = tanh_dot(A, B, C, X, Y, Z, a4);
    v = dpp_row_sum16(v);
    float ex = __expf(v);
    float e0 = __shfl(ex, 0);
    float e1 = __shfl(ex, 16);
    float e2 = __shfl(ex, 32);
    float e3 = __shfl(ex, 48);
    float4 hv = h4_to_f4(hr);
    num.x += e0 * hv.x;
    num.y += e1 * hv.y;
    num.z += e2 * hv.z;
    num.w += e3 * hv.w;
    den.x += e0; den.y += e1; den.z += e2; den.w += e3;
  }
  sm_num[w][lane] = num;
  if (lane == 0) sm_den[w] = den;
  __syncthreads();
  if (tid < 64) {
    float4 n0 = sm_num[0][tid], n1 = sm_num[1][tid];
    float4 n2 = sm_num[2][tid], n3 = sm_num[3][tid];
    float4 d0 = sm_den[0], d1 = sm_den[1], d2 = sm_den[2], d3 = sm_den[3];
    float4 ns = make_float4(n0.x + n1.x + n2.x + n3.x, n0.y + n1.y + n2.y + n3.y,
                            n0.z + n1.z + n2.z + n3.z, n0.w + n1.w + n2.w + n3.w);
    float4 ds = make_float4(d0.x + d1.x + d2.x + d3.x, d0.y + d1.y + d2.y + d3.y,
                            d0.z + d1.z + d2.z + d3.z, d0.w + d1.w + d2.w + d3.w);
    float r = 0.f;
    if (deg > 0)
      r = 0.25f * (ns.x / ds.x + ns.y / ds.y + ns.z / ds.z + ns.w / ds.w);
    out[n * 64 + tid] = r;
  }
}

// ---------------------------------------------------------------------------
extern "C" void kernel_launch(void* const* d_in, const int* in_sizes, int n_in,
                              void* d_out, int out_size, void* d_ws,
                              size_t ws_size, hipStream_t stream) {
  const float* feat = (const float*)d_in[0];
  const float* loc = (const float*)d_in[1];
  const int* src = (const int*)d_in[2];
  const int* dst = (const int*)d_in[3];
  const int* inter = (const int*)d_in[4];
  const float* Wfc = (const float*)d_in[5];
  const float* emb = (const float*)d_in[6];
  const float* G = (const float*)d_in[7];
  const float* fc1 = (const float*)d_in[8];
  const float* fc2 = (const float*)d_in[9];
  const float* fc3 = (const float*)d_in[10];
  const float* fcc = (const float*)d_in[11];
  const float* aout = (const float*)d_in[12];
  const float* bnd = (const float*)d_in[13];
  float* out = (float*)d_out;

  __half* qall = (__half*)d_ws;           // N*1024 halfs (20.48 MB)
  __half* bigWT = qall + N_NODES * QREC;  // 1024*128 halfs
  __half* U16 = bigWT + 1024 * 128;       // 3*4*2048 halfs
  uint4* ebuf = (uint4*)(U16 + 3 * H * 2048);  // N*SLOTS uint4 (10.24 MB)
  int* cnt = (int*)(ebuf + N_NODES * SLOTS);   // N ints

  hipMemsetAsync(cnt, 0, N_NODES * sizeof(int), stream);
  prep_kernel<<<12 + E_EDGES / 256, 256, 0, stream>>>(
      fc1, fc2, fc3, fcc, Wfc, G, emb, loc, src, dst, inter, bnd, bigWT, U16,
      cnt, ebuf);
  gemm_kernel<<<628, 256, 0, stream>>>(feat, bigWT, qall);
  score_agg_kernel<<<N_NODES, 256, 0, stream>>>(cnt, ebuf, qall, U16, aout,
                                                out);
}

// Round 2
// 207.574 us; speedup vs baseline: 1.1413x; 1.1413x over previous
//
#include <hip/hip_runtime.h>
#include <hip/hip_fp16.h>
#include <math.h>

#define N_NODES 10000
#define E_EDGES 160000
#define DMODEL 64
#define H 4
#define NBOUND 31
#define SLOTS 64  // fixed per-node CSR bucket; P(deg>64)<1e-11 for multinomial(16)
// qall record per node (fp16, 1024 halves):
//  [0:256)    h  d-major: offset d*4 + head   (one 8B load = all 4 heads at d)
//  [256:512)  q1: 256 + head*64 + d
//  [512:768)  q2: 512 + head*64 + d
//  [768:1024) q3: 768 + head*64 + d
#define QREC 1024

typedef _Float16 half8 __attribute__((ext_vector_type(8)));
typedef float floatx4 __attribute__((ext_vector_type(4)));

// ---------------------------------------------------------------------------
// LDS 64-wide microtile helper: o[r] = sum_t A[i0+r][t] * B[t][j].
// ---------------------------------------------------------------------------
__device__ __forceinline__ void mm4(const float* __restrict__ S, int aoff,
                                    int astride, int boff, int i0, int j,
                                    int Kdim, float o[4]) {
  float a0 = 0.f, a1 = 0.f, a2 = 0.f, a3 = 0.f;
  for (int t4 = 0; t4 < (Kdim >> 2); ++t4) {
    float4 f0 = *(const float4*)&S[aoff + (i0 + 0) * astride + t4 * 4];
    float4 f1 = *(const float4*)&S[aoff + (i0 + 1) * astride + t4 * 4];
    float4 f2 = *(const float4*)&S[aoff + (i0 + 2) * astride + t4 * 4];
    float4 f3 = *(const float4*)&S[aoff + (i0 + 3) * astride + t4 * 4];
    float b0 = S[boff + (t4 * 4 + 0) * 64 + j];
    float b1 = S[boff + (t4 * 4 + 1) * 64 + j];
    float b2 = S[boff + (t4 * 4 + 2) * 64 + j];
    float b3 = S[boff + (t4 * 4 + 3) * 64 + j];
    a0 += f0.x * b0 + f0.y * b1 + f0.z * b2 + f0.w * b3;
    a1 += f1.x * b0 + f1.y * b1 + f1.z * b2 + f1.w * b3;
    a2 += f2.x * b0 + f2.y * b1 + f2.z * b2 + f2.w * b3;
    a3 += f3.x * b0 + f3.y * b1 + f3.z * b2 + f3.w * b3;
  }
  o[0] = a0; o[1] = a1; o[2] = a2; o[3] = a3;
}

__device__ __forceinline__ int didx(const float* __restrict__ bnd2, float d) {
  int g = (int)(d * 10.0f);
  g = (g < 0) ? 0 : ((g > 31) ? 31 : g);
  g += (bnd2[g + 1] < d) ? 1 : 0;
  g -= (bnd2[g] >= d) ? 1 : 0;
  return g;
}

// ---------------------------------------------------------------------------
// D1: EDGE kernel (standalone, tiny resources -> max occupancy). dist ->
// bucket index, CSR scatter of packed 16B record into
// ebuf[t*SLOTS + atomicAdd(cnt[t])].
// record uint4: x = s | it0<<16 ; y = it1 | it2<<16 ;
//               z = it3 | i1<<16 | q2_0<<21 | q__0<<26 ;
//               w = (q2_h | q__h<<5) << ((h-1)*10)  for h=1..3
// ---------------------------------------------------------------------------
__global__ __launch_bounds__(256) void edge_kernel(
    const float* __restrict__ pos, const int* __restrict__ src,
    const int* __restrict__ dst, const int* __restrict__ inter,
    const float* __restrict__ boundaries, int* __restrict__ cnt,
    uint4* __restrict__ ebuf) {
  __shared__ float Sb[48];
  int tid = threadIdx.x;
  if (tid < NBOUND) Sb[tid + 1] = boundaries[tid];
  if (tid == NBOUND) { Sb[0] = -INFINITY; Sb[32] = INFINITY; }
  __syncthreads();
  int e = blockIdx.x * 256 + tid;  // 625*256 == E exactly
  int s = src[e], t = dst[e];
  int4 iv = *(const int4*)&inter[e * 4];
  int itarr[4] = {iv.x, iv.y, iv.z, iv.w};
  float sx = pos[s * 3], sy = pos[s * 3 + 1], sz = pos[s * 3 + 2];
  float tx = pos[t * 3], ty = pos[t * 3 + 1], tz = pos[t * 3 + 2];
  float dx = tx - sx, dy = ty - sy, dz = tz - sz;
  float dist1 = sqrtf(dx * dx + dy * dy + dz * dz);
  unsigned i1 = (unsigned)didx(Sb, dist1);
  unsigned w3 = 0, q20 = 0, q_0 = 0;
  #pragma unroll
  for (int hh = 0; hh < 4; ++hh) {
    int it = itarr[hh];
    float ix = pos[it * 3], iy = pos[it * 3 + 1], iz = pos[it * 3 + 2];
    float ax = tx - ix, ay = ty - iy, az = tz - iz;
    float dist2 = sqrtf(ax * ax + ay * ay + az * az);
    float bx = sx - ix, by = sy - iy, bz = sz - iz;
    float dist_ = sqrtf(bx * bx + by * by + bz * bz);
    unsigned idx2 = (unsigned)didx(Sb, dist2);
    unsigned idx_ = (unsigned)didx(Sb, dist_);
    if (hh == 0) { q20 = idx2; q_0 = idx_; }
    else w3 |= (idx2 | (idx_ << 5)) << ((hh - 1) * 10);
  }
  uint4 rec;
  rec.x = (unsigned)s | ((unsigned)itarr[0] << 16);
  rec.y = (unsigned)itarr[1] | ((unsigned)itarr[2] << 16);
  rec.z = (unsigned)itarr[3] | (i1 << 16) | (q20 << 21) | (q_0 << 26);
  rec.w = w3;
  int p = atomicAdd(&cnt[t], 1);
  if (p < SLOTS) ebuf[t * SLOTS + p] = rec;
}

// ---------------------------------------------------------------------------
// D2: fat per-(k,h) precompute (B1->WC->B2->GB->U). 12 blocks only.
// ---------------------------------------------------------------------------
__global__ __launch_bounds__(256) void prep_kernel(
    const float* __restrict__ fc1, const float* __restrict__ fc2,
    const float* __restrict__ fc3, const float* __restrict__ fcc,
    const float* __restrict__ Wfc, const float* __restrict__ G,
    const float* __restrict__ emb, __half* __restrict__ bigWT,
    __half* __restrict__ U16) {
  __shared__ __align__(16) float S[12288];
  int bi = blockIdx.x;
  int tid = threadIdx.x;
  int k = bi >> 2, h = bi & 3;
  const float* fck = (k == 0) ? fc1 : (k == 1) ? fc2 : fc3;
  fck += h * 128 * 64;
  const float* F = fcc + h * 192 * 64 + k * 64 * 64;
  int j = tid & 63, ig = tid >> 6;
  float o[4];
  // stage F -> S[0:4096), fckU -> S[4096:8192)
  #pragma unroll
  for (int u = 0; u < 4; ++u) {
    ((float4*)S)[u * 256 + tid] = ((const float4*)F)[u * 256 + tid];
    ((float4*)(S + 4096))[u * 256 + tid] = ((const float4*)fck)[u * 256 + tid];
  }
  __syncthreads();
  // B1 = fckU @ F -> S[8192)
  #pragma unroll
  for (int rg = 0; rg < 4; ++rg) {
    int i0 = ig * 16 + rg * 4;
    mm4(S, 4096, 64, 0, i0, j, 64, o);
    S[8192 + (i0 + 0) * 64 + j] = o[0];
    S[8192 + (i0 + 1) * 64 + j] = o[1];
    S[8192 + (i0 + 2) * 64 + j] = o[2];
    S[8192 + (i0 + 3) * 64 + j] = o[3];
  }
  __syncthreads();
  // stage WfcU (rows 0..63, col slice h) -> S[4096)
  #pragma unroll
  for (int u = 0; u < 4; ++u) {
    int fi = u * 256 + tid;
    int i = fi >> 4, c4 = fi & 15;
    ((float4*)(S + 4096))[fi] = ((const float4*)(Wfc + i * 256 + h * 64))[c4];
  }
  __syncthreads();
  if (k == 0) {
    #pragma unroll
    for (int u = 0; u < 16; ++u) {
      int idx = u * 256 + tid;
      int i = idx >> 6, jj = idx & 63;
      bigWT[(h * 64 + jj) * 128 + i] = __float2half(S[4096 + idx]);
    }
  }
  // WC0 = WfcU @ B1 -> bigWT cols 0..63
  #pragma unroll
  for (int rg = 0; rg < 4; ++rg) {
    int i0 = ig * 16 + rg * 4;
    mm4(S, 4096, 64, 8192, i0, j, 64, o);
    int rb = ((k + 1) * 256 + h * 64 + j) * 128;
    bigWT[rb + i0 + 0] = __float2half(o[0]);
    bigWT[rb + i0 + 1] = __float2half(o[1]);
    bigWT[rb + i0 + 2] = __float2half(o[2]);
    bigWT[rb + i0 + 3] = __float2half(o[3]);
  }
  __syncthreads();
  // stage WfcL (rows 64..127) -> S[4096)
  #pragma unroll
  for (int u = 0; u < 4; ++u) {
    int fi = u * 256 + tid;
    int i = fi >> 4, c4 = fi & 15;
    ((float4*)(S + 4096))[fi] =
        ((const float4*)(Wfc + (64 + i) * 256 + h * 64))[c4];
  }
  __syncthreads();
  if (k == 0) {
    #pragma unroll
    for (int u = 0; u < 16; ++u) {
      int idx = u * 256 + tid;
      int i = idx >> 6, jj = idx & 63;
      bigWT[(h * 64 + jj) * 128 + 64 + i] = __float2half(S[4096 + idx]);
    }
  }
  // WC1 = WfcL @ B1 -> bigWT cols 64..127
  #pragma unroll
  for (int rg = 0; rg < 4; ++rg) {
    int i0 = ig * 16 + rg * 4;
    mm4(S, 4096, 64, 8192, i0, j, 64, o);
    int rb = ((k + 1) * 256 + h * 64 + j) * 128;
    bigWT[rb + 64 + i0 + 0] = __float2half(o[0]);
    bigWT[rb + 64 + i0 + 1] = __float2half(o[1]);
    bigWT[rb + 64 + i0 + 2] = __float2half(o[2]);
    bigWT[rb + 64 + i0 + 3] = __float2half(o[3]);
  }
  __syncthreads();
  // stage fckL (rows 64..127) -> S[4096)
  #pragma unroll
  for (int u = 0; u < 4; ++u)
    ((float4*)(S + 4096))[u * 256 + tid] =
        ((const float4*)(fck + 4096))[u * 256 + tid];
  __syncthreads();
  // B2 = fckL @ F -> S[8192)
  #pragma unroll
  for (int rg = 0; rg < 4; ++rg) {
    int i0 = ig * 16 + rg * 4;
    mm4(S, 4096, 64, 0, i0, j, 64, o);
    S[8192 + (i0 + 0) * 64 + j] = o[0];
    S[8192 + (i0 + 1) * 64 + j] = o[1];
    S[8192 + (i0 + 2) * 64 + j] = o[2];
    S[8192 + (i0 + 3) * 64 + j] = o[3];
  }
  __syncthreads();
  // stage G_h -> S[0:2048), emb -> S[2048:3072)
  #pragma unroll
  for (int u = 0; u < 2; ++u)
    ((float4*)S)[u * 256 + tid] = ((const float4*)(G + h * 2048))[u * 256 + tid];
  ((float4*)(S + 2048))[tid] = ((const float4*)emb)[tid];
  __syncthreads();
  // GB = G @ B2 (32x64) -> S[3072)
  #pragma unroll
  for (int rg = 0; rg < 2; ++rg) {
    int i0 = ig * 8 + rg * 4;
    mm4(S, 0, 64, 8192, i0, j, 64, o);
    S[3072 + (i0 + 0) * 64 + j] = o[0];
    S[3072 + (i0 + 1) * 64 + j] = o[1];
    S[3072 + (i0 + 2) * 64 + j] = o[2];
    S[3072 + (i0 + 3) * 64 + j] = o[3];
  }
  __syncthreads();
  // U = emb @ GB (32x64, K=32) -> U16
  #pragma unroll
  for (int rg = 0; rg < 2; ++rg) {
    int i0 = ig * 8 + rg * 4;
    mm4(S, 2048, 32, 3072, i0, j, 32, o);
    int base = k * 8192 + h * 2048;
    U16[base + (i0 + 0) * 64 + j] = __float2half(o[0]);
    U16[base + (i0 + 1) * 64 + j] = __float2half(o[1]);
    U16[base + (i0 + 2) * 64 + j] = __float2half(o[2]);
    U16[base + (i0 + 3) * 64 + j] = __float2half(o[3]);
  }
}

// ---------------------------------------------------------------------------
// D3: MFMA gemm (64 x 256 region tiles, LDS-staged epilogue). A-fragments
// read feat fp32 directly and convert in-register.
// ---------------------------------------------------------------------------
#define EROW 264  // epilogue LDS row stride in halves

__global__ __launch_bounds__(256) void gemm_kernel(
    const float* __restrict__ feat, const __half* __restrict__ bigWT,
    __half* __restrict__ qall) {
  __shared__ __align__(16) __half Esm[4][16][EROW];
  int bi = blockIdx.x;
  int tid = threadIdx.x;
  int bx = bi % 157, by = bi / 157;  // by = region 0..3
  int wv = tid >> 6, l = tid & 63;
  int m0 = bx * 64 + wv * 16;
  int n0 = by * 256;
  int lm = l & 15, lk = (l >> 4) * 8;
  int arow = m0 + lm;
  if (arow >= N_NODES) arow = N_NODES - 1;
  const float* fp = feat + arow * 128 + lk;
  const _Float16* bp = (const _Float16*)bigWT + lk;
  half8 a[4];
  #pragma unroll
  for (int kt = 0; kt < 4; ++kt) {
    float4 u0 = *(const float4*)(fp + kt * 32);
    float4 u1 = *(const float4*)(fp + kt * 32 + 4);
    half8 t;
    t[0] = (_Float16)u0.x; t[1] = (_Float16)u0.y;
    t[2] = (_Float16)u0.z; t[3] = (_Float16)u0.w;
    t[4] = (_Float16)u1.x; t[5] = (_Float16)u1.y;
    t[6] = (_Float16)u1.z; t[7] = (_Float16)u1.w;
    a[kt] = t;
  }
  #pragma unroll
  for (int nt = 0; nt < 16; ++nt) {
    floatx4 acc = (floatx4){0.f, 0.f, 0.f, 0.f};
    #pragma unroll
    for (int kt = 0; kt < 4; ++kt) {
      half8 b = *(const half8*)(bp + (n0 + nt * 16 + lm) * 128 + kt * 32);
      acc = __builtin_amdgcn_mfma_f32_16x16x32_f16(a[kt], b, acc, 0, 0, 0);
    }
    int dd = nt * 16 + lm;  // col within region, 0..255
    int o = (by == 0) ? ((dd & 63) * 4 + (dd >> 6)) : dd;
    #pragma unroll
    for (int r4 = 0; r4 < 4; ++r4)
      Esm[wv][(l >> 4) * 4 + r4][o] = __float2half(acc[r4]);
  }
  __syncthreads();
  int row = l >> 2;       // 0..15
  int j0 = (l & 3) * 64;  // 0,64,128,192
  int m = m0 + row;
  if (m < N_NODES) {
    #pragma unroll
    for (int u = 0; u < 8; ++u) {
      uint4 v = *(const uint4*)&Esm[wv][row][j0 + u * 8];
      *(uint4*)&qall[m * QREC + by * 256 + j0 + u * 8] = v;
    }
  }
}

// ---------------------------------------------------------------------------
// D4: FUSED score + aggregation. One block per dst node; 4 waves stride the
// node's CSR bucket, TWO edges in flight per wave per iter (independent
// gather chains -> 2x MLP). q3[dst] loaded once per block. Max-free softmax.
// ---------------------------------------------------------------------------
__device__ __forceinline__ float dpp_row_sum16(float v) {
  int x;
  x = __builtin_amdgcn_update_dpp(0, __float_as_int(v), 0x128, 0xf, 0xf, true);
  v += __int_as_float(x);
  x = __builtin_amdgcn_update_dpp(0, __float_as_int(v), 0x124, 0xf, 0xf, true);
  v += __int_as_float(x);
  x = __builtin_amdgcn_update_dpp(0, __float_as_int(v), 0x122, 0xf, 0xf, true);
  v += __int_as_float(x);
  x = __builtin_amdgcn_update_dpp(0, __float_as_int(v), 0x121, 0xf, 0xf, true);
  v += __int_as_float(x);
  return v;
}

union H4u { uint2 u; __half2 h[2]; };

__device__ __forceinline__ float tanh_dot(H4u A, H4u B, H4u C, H4u X, H4u Y,
                                          H4u Z, float4 a4) {
  __half2 z0 = __hadd2(__hadd2(A.h[0], B.h[0]), __hadd2(C.h[0], X.h[0]));
  z0 = __hadd2(z0, __hadd2(Y.h[0], Z.h[0]));
  __half2 z1 = __hadd2(__hadd2(A.h[1], B.h[1]), __hadd2(C.h[1], X.h[1]));
  z1 = __hadd2(z1, __hadd2(Y.h[1], Z.h[1]));
  float2 f0 = __half22float2(z0);
  float2 f1 = __half22float2(z1);
  const float K = 2.885390082f;  // 2*log2(e)
  float p0 = __builtin_amdgcn_exp2f(f0.x * K);
  float p1 = __builtin_amdgcn_exp2f(f0.y * K);
  float p2 = __builtin_amdgcn_exp2f(f1.x * K);
  float p3 = __builtin_amdgcn_exp2f(f1.y * K);
  float r0 = __builtin_amdgcn_rcpf(p0 + 1.0f);
  float r1 = __builtin_amdgcn_rcpf(p1 + 1.0f);
  float r2 = __builtin_amdgcn_rcpf(p2 + 1.0f);
  float r3 = __builtin_amdgcn_rcpf(p3 + 1.0f);
  float dot = a4.x * r0;
  dot = fmaf(a4.y, r1, dot);
  dot = fmaf(a4.z, r2, dot);
  dot = fmaf(a4.w, r3, dot);
  float asum = (a4.x + a4.y) + (a4.z + a4.w);
  return fmaf(-2.0f, dot, asum);
}

__device__ __forceinline__ float4 h4_to_f4(uint2 u) {
  union { uint2 ui; __half2 h[2]; } cc;
  cc.ui = u;
  float2 a = __half22float2(cc.h[0]);
  float2 b = __half22float2(cc.h[1]);
  return make_float4(a.x, a.y, b.x, b.y);
}

__device__ __forceinline__ void dec_rec(uint4 r, int h, int* s, int* it,
                                        unsigned* i1, unsigned* q2,
                                        unsigned* q_) {
  *s = (int)(r.x & 0xffff);
  *it = (h == 0) ? (int)(r.x >> 16)
      : (h == 1) ? (int)(r.y & 0xffff)
      : (h == 2) ? (int)(r.y >> 16) : (int)(r.z & 0xffff);
  *i1 = (r.z >> 16) & 31;
  if (h == 0) {
    *q2 = (r.z >> 21) & 31;
    *q_ = (r.z >> 26) & 31;
  } else {
    unsigned f = r.w >> ((h - 1) * 10);
    *q2 = f & 31;
    *q_ = (f >> 5) & 31;
  }
}

__device__ __forceinline__ void gather_edge(
    const __half* __restrict__ qall, const __half* __restrict__ U16, int h,
    int c, int lane, int s, int it, unsigned i1, unsigned q2, unsigned q_,
    H4u* A, H4u* B, H4u* X, H4u* Y, H4u* Z, uint2* hr) {
  A->u = *(const uint2*)(qall + s * QREC + 256 + h * 64 + c * 4);
  B->u = *(const uint2*)(qall + it * QREC + 512 + h * 64 + c * 4);
  X->u = *(const uint2*)(U16 + (h * 32 + (int)i1) * 64 + c * 4);
  Y->u = *(const uint2*)(U16 + 8192 + (h * 32 + (int)q2) * 64 + c * 4);
  Z->u = *(const uint2*)(U16 + 16384 + (h * 32 + (int)q_) * 64 + c * 4);
  *hr = *(const uint2*)(qall + s * QREC + lane * 4);  // h[d=lane][4 heads]
}

__global__ __launch_bounds__(256) void score_agg_kernel(
    const int* __restrict__ cnt, const uint4* __restrict__ ebuf,
    const __half* __restrict__ qall, const __half* __restrict__ U16,
    const float* __restrict__ aout, float* __restrict__ out) {
  __shared__ uint4 recs[SLOTS];
  __shared__ float4 sm_num[4][64];
  __shared__ float4 sm_den[4];
  int tid = threadIdx.x;
  int w = tid >> 6, lane = tid & 63;
  int h = lane >> 4, c = lane & 15;
  int n = blockIdx.x;
  int deg = cnt[n];
  if (deg > SLOTS) deg = SLOTS;
  // stage the node's edge records into LDS
  if (tid < deg) recs[tid] = ebuf[n * SLOTS + tid];
  // per-block invariants: q3[dst] fragment + attn_out column
  H4u C;
  C.u = *(const uint2*)(qall + n * QREC + 768 + h * 64 + c * 4);
  const float4 a4 = *((const float4*)(aout + h * 64) + c);
  __syncthreads();
  float4 num = make_float4(0.f, 0.f, 0.f, 0.f);
  float4 den = make_float4(0.f, 0.f, 0.f, 0.f);
  for (int i = w; i < deg; i += 8) {
    int iB = i + 4;
    int vB = (iB < deg);  // wave-uniform
    uint4 rA = recs[i];
    uint4 rB = recs[vB ? iB : i];
    int sA, itA, sB, itB;
    unsigned i1A, q2A, q_A, i1B, q2B, q_B;
    dec_rec(rA, h, &sA, &itA, &i1A, &q2A, &q_A);
    dec_rec(rB, h, &sB, &itB, &i1B, &q2B, &q_B);
    H4u A0, B0, X0, Y0, Z0, A1, B1, X1, Y1, Z1;
    uint2 hr0, hr1;
    gather_edge(qall, U16, h, c, lane, sA, itA, i1A, q2A, q_A, &A0, &B0, &X0,
                &Y0, &Z0, &hr0);
    gather_edge(qall, U16, h, c, lane, sB, itB, i1B, q2B, q_B, &A1, &B1, &X1,
                &Y1, &Z1, &hr1);
    float v0 = tanh_dot(A0, B0, C, X0, Y0, Z0, a4);
    float v1 = tanh_dot(A1, B1, C, X1, Y1, Z1, a4);
    v0 = dpp_row_sum16(v0);
    v1 = dpp_row_sum16(v1);
    float ex0 = __expf(v0);
    float ex1 = vB ? __expf(v1) : 0.f;
    float4 hv0 = h4_to_f4(hr0);
    float4 hv1 = h4_to_f4(hr1);
    float e00 = __shfl(ex0, 0), e01 = __shfl(ex0, 16);
    float e02 = __shfl(ex0, 32), e03 = __shfl(ex0, 48);
    float e10 = __shfl(ex1, 0), e11 = __shfl(ex1, 16);
    float e12 = __shfl(ex1, 32), e13 = __shfl(ex1, 48);
    num.x += e00 * hv0.x + e10 * hv1.x;
    num.y += e01 * hv0.y + e11 * hv1.y;
    num.z += e02 * hv0.z + e12 * hv1.z;
    num.w += e03 * hv0.w + e13 * hv1.w;
    den.x += e00 + e10;
    den.y += e01 + e11;
    den.z += e02 + e12;
    den.w += e03 + e13;
  }
  sm_num[w][lane] = num;
  if (lane == 0) sm_den[w] = den;
  __syncthreads();
  if (tid < 64) {
    float4 n0 = sm_num[0][tid], n1 = sm_num[1][tid];
    float4 n2 = sm_num[2][tid], n3 = sm_num[3][tid];
    float4 d0 = sm_den[0], d1 = sm_den[1], d2 = sm_den[2], d3 = sm_den[3];
    float4 ns = make_float4(n0.x + n1.x + n2.x + n3.x, n0.y + n1.y + n2.y + n3.y,
                            n0.z + n1.z + n2.z + n3.z, n0.w + n1.w + n2.w + n3.w);
    float4 ds = make_float4(d0.x + d1.x + d2.x + d3.x, d0.y + d1.y + d2.y + d3.y,
                            d0.z + d1.z + d2.z + d3.z, d0.w + d1.w + d2.w + d3.w);
    float r = 0.f;
    if (deg > 0)
      r = 0.25f * (ns.x / ds.x + ns.y / ds.y + ns.z / ds.z + ns.w / ds.w);
    out[n * 64 + tid] = r;
  }
}

// ---------------------------------------------------------------------------
extern "C" void kernel_launch(void* const* d_in, const int* in_sizes, int n_in,
                              void* d_out, int out_size, void* d_ws,
                              size_t ws_size, hipStream_t stream) {
  const float* feat = (const float*)d_in[0];
  const float* loc = (const float*)d_in[1];
  const int* src = (const int*)d_in[2];
  const int* dst = (const int*)d_in[3];
  const int* inter = (const int*)d_in[4];
  const float* Wfc = (const float*)d_in[5];
  const float* emb = (const float*)d_in[6];
  const float* G = (const float*)d_in[7];
  const float* fc1 = (const float*)d_in[8];
  const float* fc2 = (const float*)d_in[9];
  const float* fc3 = (const float*)d_in[10];
  const float* fcc = (const float*)d_in[11];
  const float* aout = (const float*)d_in[12];
  const float* bnd = (const float*)d_in[13];
  float* out = (float*)d_out;

  __half* qall = (__half*)d_ws;           // N*1024 halfs (20.48 MB)
  __half* bigWT = qall + N_NODES * QREC;  // 1024*128 halfs
  __half* U16 = bigWT + 1024 * 128;       // 3*4*2048 halfs
  uint4* ebuf = (uint4*)(U16 + 3 * H * 2048);  // N*SLOTS uint4 (10.24 MB)
  int* cnt = (int*)(ebuf + N_NODES * SLOTS);   // N ints

  hipMemsetAsync(cnt, 0, N_NODES * sizeof(int), stream);
  edge_kernel<<<E_EDGES / 256, 256, 0, stream>>>(loc, src, dst, inter, bnd,
                                                 cnt, ebuf);
  prep_kernel<<<12, 256, 0, stream>>>(fc1, fc2, fc3, fcc, Wfc, G, emb, bigWT,
                                      U16);
  gemm_kernel<<<628, 256, 0, stream>>>(feat, bigWT, qall);
  score_agg_kernel<<<N_NODES, 256, 0, stream>>>(cnt, ebuf, qall, U16, aout,
                                                out);
}

// Round 3
// 191.285 us; speedup vs baseline: 1.2385x; 1.0852x over previous
//
#include <hip/hip_runtime.h>
#include <hip/hip_fp16.h>
#include <math.h>

#define N_NODES 10000
#define E_EDGES 160000
#define DMODEL 64
#define H 4
#define NBOUND 31
#define SLOTS 64  // fixed per-node CSR bucket; P(deg>64)<1e-11 for multinomial(16)
// qall record per node (fp16, 1024 halves):
//  [0:256)    h  d-major: offset d*4 + head   (one 8B load = all 4 heads at d)
//  [256:512)  q1: 256 + head*64 + d
//  [512:768)  q2: 512 + head*64 + d
//  [768:1024) q3: 768 + head*64 + d
#define QREC 1024

typedef _Float16 half8 __attribute__((ext_vector_type(8)));
typedef float floatx4 __attribute__((ext_vector_type(4)));

// ---------------------------------------------------------------------------
// LDS 64-wide microtile helper: o[r] = sum_t A[i0+r][t] * B[t][j].
// ---------------------------------------------------------------------------
__device__ __forceinline__ void mm4(const float* __restrict__ S, int aoff,
                                    int astride, int boff, int i0, int j,
                                    int Kdim, float o[4]) {
  float a0 = 0.f, a1 = 0.f, a2 = 0.f, a3 = 0.f;
  for (int t4 = 0; t4 < (Kdim >> 2); ++t4) {
    float4 f0 = *(const float4*)&S[aoff + (i0 + 0) * astride + t4 * 4];
    float4 f1 = *(const float4*)&S[aoff + (i0 + 1) * astride + t4 * 4];
    float4 f2 = *(const float4*)&S[aoff + (i0 + 2) * astride + t4 * 4];
    float4 f3 = *(const float4*)&S[aoff + (i0 + 3) * astride + t4 * 4];
    float b0 = S[boff + (t4 * 4 + 0) * 64 + j];
    float b1 = S[boff + (t4 * 4 + 1) * 64 + j];
    float b2 = S[boff + (t4 * 4 + 2) * 64 + j];
    float b3 = S[boff + (t4 * 4 + 3) * 64 + j];
    a0 += f0.x * b0 + f0.y * b1 + f0.z * b2 + f0.w * b3;
    a1 += f1.x * b0 + f1.y * b1 + f1.z * b2 + f1.w * b3;
    a2 += f2.x * b0 + f2.y * b1 + f2.z * b2 + f2.w * b3;
    a3 += f3.x * b0 + f3.y * b1 + f3.z * b2 + f3.w * b3;
  }
  o[0] = a0; o[1] = a1; o[2] = a2; o[3] = a3;
}

__device__ __forceinline__ int didx(const float* __restrict__ bnd2, float d) {
  int g = (int)(d * 10.0f);
  g = (g < 0) ? 0 : ((g > 31) ? 31 : g);
  g += (bnd2[g + 1] < d) ? 1 : 0;
  g -= (bnd2[g] >= d) ? 1 : 0;
  return g;
}

// ---------------------------------------------------------------------------
// D1: EDGE kernel (standalone, tiny resources -> max occupancy). dist ->
// bucket index, CSR scatter of packed 16B record into
// ebuf[t*SLOTS + atomicAdd(cnt[t])].
// record uint4: x = s | it0<<16 ; y = it1 | it2<<16 ;
//               z = it3 | i1<<16 | q2_0<<21 | q__0<<26 ;
//               w = (q2_h | q__h<<5) << ((h-1)*10)  for h=1..3
// ---------------------------------------------------------------------------
__global__ __launch_bounds__(256) void edge_kernel(
    const float* __restrict__ pos, const int* __restrict__ src,
    const int* __restrict__ dst, const int* __restrict__ inter,
    const float* __restrict__ boundaries, int* __restrict__ cnt,
    uint4* __restrict__ ebuf) {
  __shared__ float Sb[48];
  int tid = threadIdx.x;
  if (tid < NBOUND) Sb[tid + 1] = boundaries[tid];
  if (tid == NBOUND) { Sb[0] = -INFINITY; Sb[32] = INFINITY; }
  __syncthreads();
  int e = blockIdx.x * 256 + tid;  // 625*256 == E exactly
  int s = src[e], t = dst[e];
  int4 iv = *(const int4*)&inter[e * 4];
  int itarr[4] = {iv.x, iv.y, iv.z, iv.w};
  float sx = pos[s * 3], sy = pos[s * 3 + 1], sz = pos[s * 3 + 2];
  float tx = pos[t * 3], ty = pos[t * 3 + 1], tz = pos[t * 3 + 2];
  float dx = tx - sx, dy = ty - sy, dz = tz - sz;
  float dist1 = sqrtf(dx * dx + dy * dy + dz * dz);
  unsigned i1 = (unsigned)didx(Sb, dist1);
  unsigned w3 = 0, q20 = 0, q_0 = 0;
  #pragma unroll
  for (int hh = 0; hh < 4; ++hh) {
    int it = itarr[hh];
    float ix = pos[it * 3], iy = pos[it * 3 + 1], iz = pos[it * 3 + 2];
    float ax = tx - ix, ay = ty - iy, az = tz - iz;
    float dist2 = sqrtf(ax * ax + ay * ay + az * az);
    float bx = sx - ix, by = sy - iy, bz = sz - iz;
    float dist_ = sqrtf(bx * bx + by * by + bz * bz);
    unsigned idx2 = (unsigned)didx(Sb, dist2);
    unsigned idx_ = (unsigned)didx(Sb, dist_);
    if (hh == 0) { q20 = idx2; q_0 = idx_; }
    else w3 |= (idx2 | (idx_ << 5)) << ((hh - 1) * 10);
  }
  uint4 rec;
  rec.x = (unsigned)s | ((unsigned)itarr[0] << 16);
  rec.y = (unsigned)itarr[1] | ((unsigned)itarr[2] << 16);
  rec.z = (unsigned)itarr[3] | (i1 << 16) | (q20 << 21) | (q_0 << 26);
  rec.w = w3;
  int p = atomicAdd(&cnt[t], 1);
  if (p < SLOTS) ebuf[t * SLOTS + p] = rec;
}

// ---------------------------------------------------------------------------
// D2: fat per-(k,h) precompute, split into TWO independent chains per (k,h)
// for 2x parallelism + 512 threads (8 waves) for 2x less serial depth.
//   blocks 0..11  (chain A): B1 = fckU@F; WC0/WC1 -> bigWT (+ raw Wfc^T k==0)
//   blocks 12..23 (chain B): B2 = fckL@F; GB = G@B2; U = emb@GB -> U16
// ---------------------------------------------------------------------------
__global__ __launch_bounds__(512) void prep_kernel(
    const float* __restrict__ fc1, const float* __restrict__ fc2,
    const float* __restrict__ fc3, const float* __restrict__ fcc,
    const float* __restrict__ Wfc, const float* __restrict__ G,
    const float* __restrict__ emb, __half* __restrict__ bigWT,
    __half* __restrict__ U16) {
  __shared__ __align__(16) float S[12288];
  int bi = blockIdx.x;
  int tid = threadIdx.x;
  int chain = (bi >= 12);
  int kh = chain ? (bi - 12) : bi;
  int k = kh >> 2, h = kh & 3;
  const float* fck = (k == 0) ? fc1 : (k == 1) ? fc2 : fc3;
  fck += h * 128 * 64;
  const float* F = fcc + h * 192 * 64 + k * 64 * 64;
  int j = tid & 63, ig = tid >> 6;  // ig 0..7
  float o[4];
  if (!chain) {
    // ======== chain A: B1 -> WC0 / WC1 ========
    // stage F -> S[0:4096), fckU -> S[4096:8192)
    #pragma unroll
    for (int u = 0; u < 2; ++u) {
      ((float4*)S)[u * 512 + tid] = ((const float4*)F)[u * 512 + tid];
      ((float4*)(S + 4096))[u * 512 + tid] = ((const float4*)fck)[u * 512 + tid];
    }
    __syncthreads();
    // B1 = fckU @ F -> S[8192)
    #pragma unroll
    for (int rg = 0; rg < 2; ++rg) {
      int i0 = ig * 8 + rg * 4;
      mm4(S, 4096, 64, 0, i0, j, 64, o);
      S[8192 + (i0 + 0) * 64 + j] = o[0];
      S[8192 + (i0 + 1) * 64 + j] = o[1];
      S[8192 + (i0 + 2) * 64 + j] = o[2];
      S[8192 + (i0 + 3) * 64 + j] = o[3];
    }
    __syncthreads();
    // stage WfcU (rows 0..63, col slice h) -> S[4096)
    #pragma unroll
    for (int u = 0; u < 2; ++u) {
      int fi = u * 512 + tid;
      int i = fi >> 4, c4 = fi & 15;
      ((float4*)(S + 4096))[fi] = ((const float4*)(Wfc + i * 256 + h * 64))[c4];
    }
    __syncthreads();
    if (k == 0) {
      #pragma unroll
      for (int u = 0; u < 8; ++u) {
        int idx = u * 512 + tid;
        int i = idx >> 6, jj = idx & 63;
        bigWT[(h * 64 + jj) * 128 + i] = __float2half(S[4096 + idx]);
      }
    }
    // WC0 = WfcU @ B1 -> bigWT cols 0..63
    #pragma unroll
    for (int rg = 0; rg < 2; ++rg) {
      int i0 = ig * 8 + rg * 4;
      mm4(S, 4096, 64, 8192, i0, j, 64, o);
      int rb = ((k + 1) * 256 + h * 64 + j) * 128;
      bigWT[rb + i0 + 0] = __float2half(o[0]);
      bigWT[rb + i0 + 1] = __float2half(o[1]);
      bigWT[rb + i0 + 2] = __float2half(o[2]);
      bigWT[rb + i0 + 3] = __float2half(o[3]);
    }
    __syncthreads();
    // stage WfcL (rows 64..127) -> S[4096)
    #pragma unroll
    for (int u = 0; u < 2; ++u) {
      int fi = u * 512 + tid;
      int i = fi >> 4, c4 = fi & 15;
      ((float4*)(S + 4096))[fi] =
          ((const float4*)(Wfc + (64 + i) * 256 + h * 64))[c4];
    }
    __syncthreads();
    if (k == 0) {
      #pragma unroll
      for (int u = 0; u < 8; ++u) {
        int idx = u * 512 + tid;
        int i = idx >> 6, jj = idx & 63;
        bigWT[(h * 64 + jj) * 128 + 64 + i] = __float2half(S[4096 + idx]);
      }
    }
    // WC1 = WfcL @ B1 -> bigWT cols 64..127
    #pragma unroll
    for (int rg = 0; rg < 2; ++rg) {
      int i0 = ig * 8 + rg * 4;
      mm4(S, 4096, 64, 8192, i0, j, 64, o);
      int rb = ((k + 1) * 256 + h * 64 + j) * 128;
      bigWT[rb + 64 + i0 + 0] = __float2half(o[0]);
      bigWT[rb + 64 + i0 + 1] = __float2half(o[1]);
      bigWT[rb + 64 + i0 + 2] = __float2half(o[2]);
      bigWT[rb + 64 + i0 + 3] = __float2half(o[3]);
    }
    return;
  }
  // ======== chain B: B2 -> GB -> U ========
  // stage F -> S[0:4096), fckL (rows 64..127) -> S[4096:8192)
  #pragma unroll
  for (int u = 0; u < 2; ++u) {
    ((float4*)S)[u * 512 + tid] = ((const float4*)F)[u * 512 + tid];
    ((float4*)(S + 4096))[u * 512 + tid] =
        ((const float4*)(fck + 4096))[u * 512 + tid];
  }
  __syncthreads();
  // B2 = fckL @ F -> S[8192)
  #pragma unroll
  for (int rg = 0; rg < 2; ++rg) {
    int i0 = ig * 8 + rg * 4;
    mm4(S, 4096, 64, 0, i0, j, 64, o);
    S[8192 + (i0 + 0) * 64 + j] = o[0];
    S[8192 + (i0 + 1) * 64 + j] = o[1];
    S[8192 + (i0 + 2) * 64 + j] = o[2];
    S[8192 + (i0 + 3) * 64 + j] = o[3];
  }
  __syncthreads();
  // stage G_h -> S[0:2048), emb -> S[2048:3072)
  ((float4*)S)[tid] = ((const float4*)(G + h * 2048))[tid];
  if (tid < 256) ((float4*)(S + 2048))[tid] = ((const float4*)emb)[tid];
  __syncthreads();
  // GB = G @ B2 (32x64) -> S[3072)
  {
    int i0 = ig * 4;  // 8 igs x 4 rows = 32
    mm4(S, 0, 64, 8192, i0, j, 64, o);
    S[3072 + (i0 + 0) * 64 + j] = o[0];
    S[3072 + (i0 + 1) * 64 + j] = o[1];
    S[3072 + (i0 + 2) * 64 + j] = o[2];
    S[3072 + (i0 + 3) * 64 + j] = o[3];
  }
  __syncthreads();
  // U = emb @ GB (32x64, K=32) -> U16
  {
    int i0 = ig * 4;
    mm4(S, 2048, 32, 3072, i0, j, 32, o);
    int base = k * 8192 + h * 2048;
    U16[base + (i0 + 0) * 64 + j] = __float2half(o[0]);
    U16[base + (i0 + 1) * 64 + j] = __float2half(o[1]);
    U16[base + (i0 + 2) * 64 + j] = __float2half(o[2]);
    U16[base + (i0 + 3) * 64 + j] = __float2half(o[3]);
  }
}

// ---------------------------------------------------------------------------
// D3: MFMA gemm (64 x 256 region tiles, LDS-staged epilogue). A-fragments
// read feat fp32 directly and convert in-register.
// ---------------------------------------------------------------------------
#define EROW 264  // epilogue LDS row stride in halves

__global__ __launch_bounds__(256) void gemm_kernel(
    const float* __restrict__ feat, const __half* __restrict__ bigWT,
    __half* __restrict__ qall) {
  __shared__ __align__(16) __half Esm[4][16][EROW];
  int bi = blockIdx.x;
  int tid = threadIdx.x;
  int bx = bi % 157, by = bi / 157;  // by = region 0..3
  int wv = tid >> 6, l = tid & 63;
  int m0 = bx * 64 + wv * 16;
  int n0 = by * 256;
  int lm = l & 15, lk = (l >> 4) * 8;
  int arow = m0 + lm;
  if (arow >= N_NODES) arow = N_NODES - 1;
  const float* fp = feat + arow * 128 + lk;
  const _Float16* bp = (const _Float16*)bigWT + lk;
  half8 a[4];
  #pragma unroll
  for (int kt = 0; kt < 4; ++kt) {
    float4 u0 = *(const float4*)(fp + kt * 32);
    float4 u1 = *(const float4*)(fp + kt * 32 + 4);
    half8 t;
    t[0] = (_Float16)u0.x; t[1] = (_Float16)u0.y;
    t[2] = (_Float16)u0.z; t[3] = (_Float16)u0.w;
    t[4] = (_Float16)u1.x; t[5] = (_Float16)u1.y;
    t[6] = (_Float16)u1.z; t[7] = (_Float16)u1.w;
    a[kt] = t;
  }
  #pragma unroll
  for (int nt = 0; nt < 16; ++nt) {
    floatx4 acc = (floatx4){0.f, 0.f, 0.f, 0.f};
    #pragma unroll
    for (int kt = 0; kt < 4; ++kt) {
      half8 b = *(const half8*)(bp + (n0 + nt * 16 + lm) * 128 + kt * 32);
      acc = __builtin_amdgcn_mfma_f32_16x16x32_f16(a[kt], b, acc, 0, 0, 0);
    }
    int dd = nt * 16 + lm;  // col within region, 0..255
    int o = (by == 0) ? ((dd & 63) * 4 + (dd >> 6)) : dd;
    #pragma unroll
    for (int r4 = 0; r4 < 4; ++r4)
      Esm[wv][(l >> 4) * 4 + r4][o] = __float2half(acc[r4]);
  }
  __syncthreads();
  int row = l >> 2;       // 0..15
  int j0 = (l & 3) * 64;  // 0,64,128,192
  int m = m0 + row;
  if (m < N_NODES) {
    #pragma unroll
    for (int u = 0; u < 8; ++u) {
      uint4 v = *(const uint4*)&Esm[wv][row][j0 + u * 8];
      *(uint4*)&qall[m * QREC + by * 256 + j0 + u * 8] = v;
    }
  }
}

// ---------------------------------------------------------------------------
// D4: FUSED score + aggregation. ONE WAVE PER NODE (4 nodes/block): no
// cross-wave reduction, no hot-path barriers, wave-runtime tracks its own
// node's degree. TWO edges in flight per iter. Max-free softmax.
// ---------------------------------------------------------------------------
__device__ __forceinline__ float dpp_row_sum16(float v) {
  int x;
  x = __builtin_amdgcn_update_dpp(0, __float_as_int(v), 0x128, 0xf, 0xf, true);
  v += __int_as_float(x);
  x = __builtin_amdgcn_update_dpp(0, __float_as_int(v), 0x124, 0xf, 0xf, true);
  v += __int_as_float(x);
  x = __builtin_amdgcn_update_dpp(0, __float_as_int(v), 0x122, 0xf, 0xf, true);
  v += __int_as_float(x);
  x = __builtin_amdgcn_update_dpp(0, __float_as_int(v), 0x121, 0xf, 0xf, true);
  v += __int_as_float(x);
  return v;
}

union H4u { uint2 u; __half2 h[2]; };

__device__ __forceinline__ float tanh_dot(H4u A, H4u B, H4u C, H4u X, H4u Y,
                                          H4u Z, float4 a4) {
  __half2 z0 = __hadd2(__hadd2(A.h[0], B.h[0]), __hadd2(C.h[0], X.h[0]));
  z0 = __hadd2(z0, __hadd2(Y.h[0], Z.h[0]));
  __half2 z1 = __hadd2(__hadd2(A.h[1], B.h[1]), __hadd2(C.h[1], X.h[1]));
  z1 = __hadd2(z1, __hadd2(Y.h[1], Z.h[1]));
  float2 f0 = __half22float2(z0);
  float2 f1 = __half22float2(z1);
  const float K = 2.885390082f;  // 2*log2(e)
  float p0 = __builtin_amdgcn_exp2f(f0.x * K);
  float p1 = __builtin_amdgcn_exp2f(f0.y * K);
  float p2 = __builtin_amdgcn_exp2f(f1.x * K);
  float p3 = __builtin_amdgcn_exp2f(f1.y * K);
  float r0 = __builtin_amdgcn_rcpf(p0 + 1.0f);
  float r1 = __builtin_amdgcn_rcpf(p1 + 1.0f);
  float r2 = __builtin_amdgcn_rcpf(p2 + 1.0f);
  float r3 = __builtin_amdgcn_rcpf(p3 + 1.0f);
  float dot = a4.x * r0;
  dot = fmaf(a4.y, r1, dot);
  dot = fmaf(a4.z, r2, dot);
  dot = fmaf(a4.w, r3, dot);
  float asum = (a4.x + a4.y) + (a4.z + a4.w);
  return fmaf(-2.0f, dot, asum);
}

__device__ __forceinline__ float4 h4_to_f4(uint2 u) {
  union { uint2 ui; __half2 h[2]; } cc;
  cc.ui = u;
  float2 a = __half22float2(cc.h[0]);
  float2 b = __half22float2(cc.h[1]);
  return make_float4(a.x, a.y, b.x, b.y);
}

__device__ __forceinline__ void dec_rec(uint4 r, int h, int* s, int* it,
                                        unsigned* i1, unsigned* q2,
                                        unsigned* q_) {
  *s = (int)(r.x & 0xffff);
  *it = (h == 0) ? (int)(r.x >> 16)
      : (h == 1) ? (int)(r.y & 0xffff)
      : (h == 2) ? (int)(r.y >> 16) : (int)(r.z & 0xffff);
  *i1 = (r.z >> 16) & 31;
  if (h == 0) {
    *q2 = (r.z >> 21) & 31;
    *q_ = (r.z >> 26) & 31;
  } else {
    unsigned f = r.w >> ((h - 1) * 10);
    *q2 = f & 31;
    *q_ = (f >> 5) & 31;
  }
}

__device__ __forceinline__ void gather_edge(
    const __half* __restrict__ qall, const __half* __restrict__ U16, int h,
    int c, int lane, int s, int it, unsigned i1, unsigned q2, unsigned q_,
    H4u* A, H4u* B, H4u* X, H4u* Y, H4u* Z, uint2* hr) {
  A->u = *(const uint2*)(qall + s * QREC + 256 + h * 64 + c * 4);
  B->u = *(const uint2*)(qall + it * QREC + 512 + h * 64 + c * 4);
  X->u = *(const uint2*)(U16 + (h * 32 + (int)i1) * 64 + c * 4);
  Y->u = *(const uint2*)(U16 + 8192 + (h * 32 + (int)q2) * 64 + c * 4);
  Z->u = *(const uint2*)(U16 + 16384 + (h * 32 + (int)q_) * 64 + c * 4);
  *hr = *(const uint2*)(qall + s * QREC + lane * 4);  // h[d=lane][4 heads]
}

__global__ __launch_bounds__(256) void score_agg_kernel(
    const int* __restrict__ cnt, const uint4* __restrict__ ebuf,
    const __half* __restrict__ qall, const __half* __restrict__ U16,
    const float* __restrict__ aout, float* __restrict__ out) {
  __shared__ uint4 recs[4][SLOTS];
  int tid = threadIdx.x;
  int w = tid >> 6, lane = tid & 63;
  int h = lane >> 4, c = lane & 15;
  int n = blockIdx.x * 4 + w;  // 2500*4 == N exactly
  int deg = cnt[n];
  if (deg > SLOTS) deg = SLOTS;
  // stage this wave's node records (wave-local; one barrier for safety)
  if (lane < deg) recs[w][lane] = ebuf[n * SLOTS + lane];
  H4u C;
  C.u = *(const uint2*)(qall + n * QREC + 768 + h * 64 + c * 4);
  const float4 a4 = *((const float4*)(aout + h * 64) + c);
  __syncthreads();
  float4 num = make_float4(0.f, 0.f, 0.f, 0.f);
  float4 den = make_float4(0.f, 0.f, 0.f, 0.f);
  for (int i = 0; i < deg; i += 2) {
    int iB = i + 1;
    int vB = (iB < deg);  // wave-uniform
    uint4 rA = recs[w][i];
    uint4 rB = recs[w][vB ? iB : i];
    int sA, itA, sB, itB;
    unsigned i1A, q2A, q_A, i1B, q2B, q_B;
    dec_rec(rA, h, &sA, &itA, &i1A, &q2A, &q_A);
    dec_rec(rB, h, &sB, &itB, &i1B, &q2B, &q_B);
    H4u A0, B0, X0, Y0, Z0, A1, B1, X1, Y1, Z1;
    uint2 hr0, hr1;
    gather_edge(qall, U16, h, c, lane, sA, itA, i1A, q2A, q_A, &A0, &B0, &X0,
                &Y0, &Z0, &hr0);
    gather_edge(qall, U16, h, c, lane, sB, itB, i1B, q2B, q_B, &A1, &B1, &X1,
                &Y1, &Z1, &hr1);
    float v0 = tanh_dot(A0, B0, C, X0, Y0, Z0, a4);
    float v1 = tanh_dot(A1, B1, C, X1, Y1, Z1, a4);
    v0 = dpp_row_sum16(v0);
    v1 = dpp_row_sum16(v1);
    float ex0 = __expf(v0);
    float ex1 = vB ? __expf(v1) : 0.f;
    float4 hv0 = h4_to_f4(hr0);
    float4 hv1 = h4_to_f4(hr1);
    float e00 = __shfl(ex0, 0), e01 = __shfl(ex0, 16);
    float e02 = __shfl(ex0, 32), e03 = __shfl(ex0, 48);
    float e10 = __shfl(ex1, 0), e11 = __shfl(ex1, 16);
    float e12 = __shfl(ex1, 32), e13 = __shfl(ex1, 48);
    num.x += e00 * hv0.x + e10 * hv1.x;
    num.y += e01 * hv0.y + e11 * hv1.y;
    num.z += e02 * hv0.z + e12 * hv1.z;
    num.w += e03 * hv0.w + e13 * hv1.w;
    den.x += e00 + e10;
    den.y += e01 + e11;
    den.z += e02 + e12;
    den.w += e03 + e13;
  }
  // fully wave-local epilogue: lane = d, den identical across lanes
  float r = 0.f;
  if (deg > 0)
    r = 0.25f * (num.x / den.x + num.y / den.y + num.z / den.z + num.w / den.w);
  out[n * 64 + lane] = r;
}

// ---------------------------------------------------------------------------
extern "C" void kernel_launch(void* const* d_in, const int* in_sizes, int n_in,
                              void* d_out, int out_size, void* d_ws,
                              size_t ws_size, hipStream_t stream) {
  const float* feat = (const float*)d_in[0];
  const float* loc = (const float*)d_in[1];
  const int* src = (const int*)d_in[2];
  const int* dst = (const int*)d_in[3];
  const int* inter = (const int*)d_in[4];
  const float* Wfc = (const float*)d_in[5];
  const float* emb = (const float*)d_in[6];
  const float* G = (const float*)d_in[7];
  const float* fc1 = (const float*)d_in[8];
  const float* fc2 = (const float*)d_in[9];
  const float* fc3 = (const float*)d_in[10];
  const float* fcc = (const float*)d_in[11];
  const float* aout = (const float*)d_in[12];
  const float* bnd = (const float*)d_in[13];
  float* out = (float*)d_out;

  __half* qall = (__half*)d_ws;           // N*1024 halfs (20.48 MB)
  __half* bigWT = qall + N_NODES * QREC;  // 1024*128 halfs
  __half* U16 = bigWT + 1024 * 128;       // 3*4*2048 halfs
  uint4* ebuf = (uint4*)(U16 + 3 * H * 2048);  // N*SLOTS uint4 (10.24 MB)
  int* cnt = (int*)(ebuf + N_NODES * SLOTS);   // N ints

  hipMemsetAsync(cnt, 0, N_NODES * sizeof(int), stream);
  edge_kernel<<<E_EDGES / 256, 256, 0, stream>>>(loc, src, dst, inter, bnd,
                                                 cnt, ebuf);
  prep_kernel<<<24, 512, 0, stream>>>(fc1, fc2, fc3, fcc, Wfc, G, emb, bigWT,
                                      U16);
  gemm_kernel<<<628, 256, 0, stream>>>(feat, bigWT, qall);
  score_agg_kernel<<<N_NODES / 4, 256, 0, stream>>>(cnt, ebuf, qall, U16, aout,
                                                    out);
}

// Round 4
// 184.367 us; speedup vs baseline: 1.2849x; 1.0375x over previous
//
#include <hip/hip_runtime.h>
#include <hip/hip_fp16.h>
#include <math.h>

#define N_NODES 10000
#define E_EDGES 160000
#define DMODEL 64
#define H 4
#define NBOUND 31
#define SLOTS 64  // fixed per-node CSR bucket; P(deg>64)<1e-11 for multinomial(16)
// qall record per node (fp16, 1024 halves):
//  [0:256)    h  d-major: offset d*4 + head   (one 8B load = all 4 heads at d)
//  [256:512)  q1: 256 + head*64 + d
//  [512:768)  q2: 512 + head*64 + d
//  [768:1024) q3: 768 + head*64 + d
#define QREC 1024

typedef _Float16 half8 __attribute__((ext_vector_type(8)));
typedef float floatx4 __attribute__((ext_vector_type(4)));

// ---------------------------------------------------------------------------
// LDS 64-wide microtile helper: o[r] = sum_t A[i0+r][t] * B[t][j].
// ---------------------------------------------------------------------------
__device__ __forceinline__ void mm4(const float* __restrict__ S, int aoff,
                                    int astride, int boff, int i0, int j,
                                    int Kdim, float o[4]) {
  float a0 = 0.f, a1 = 0.f, a2 = 0.f, a3 = 0.f;
  for (int t4 = 0; t4 < (Kdim >> 2); ++t4) {
    float4 f0 = *(const float4*)&S[aoff + (i0 + 0) * astride + t4 * 4];
    float4 f1 = *(const float4*)&S[aoff + (i0 + 1) * astride + t4 * 4];
    float4 f2 = *(const float4*)&S[aoff + (i0 + 2) * astride + t4 * 4];
    float4 f3 = *(const float4*)&S[aoff + (i0 + 3) * astride + t4 * 4];
    float b0 = S[boff + (t4 * 4 + 0) * 64 + j];
    float b1 = S[boff + (t4 * 4 + 1) * 64 + j];
    float b2 = S[boff + (t4 * 4 + 2) * 64 + j];
    float b3 = S[boff + (t4 * 4 + 3) * 64 + j];
    a0 += f0.x * b0 + f0.y * b1 + f0.z * b2 + f0.w * b3;
    a1 += f1.x * b0 + f1.y * b1 + f1.z * b2 + f1.w * b3;
    a2 += f2.x * b0 + f2.y * b1 + f2.z * b2 + f2.w * b3;
    a3 += f3.x * b0 + f3.y * b1 + f3.z * b2 + f3.w * b3;
  }
  o[0] = a0; o[1] = a1; o[2] = a2; o[3] = a3;
}

__device__ __forceinline__ int didx(const float* __restrict__ bnd2, float d) {
  int g = (int)(d * 10.0f);
  g = (g < 0) ? 0 : ((g > 31) ? 31 : g);
  g += (bnd2[g + 1] < d) ? 1 : 0;
  g -= (bnd2[g] >= d) ? 1 : 0;
  return g;
}

// ---------------------------------------------------------------------------
// D1: prep. blocks 0..11 chain A (B1->WC0/WC1 -> bigWT), 12..23 chain B
// (B2->GB->U -> U16), 24..43 zero cnt (replaces memset dispatch).
// ---------------------------------------------------------------------------
__global__ __launch_bounds__(512) void prep_kernel(
    const float* __restrict__ fc1, const float* __restrict__ fc2,
    const float* __restrict__ fc3, const float* __restrict__ fcc,
    const float* __restrict__ Wfc, const float* __restrict__ G,
    const float* __restrict__ emb, __half* __restrict__ bigWT,
    __half* __restrict__ U16, int* __restrict__ cnt) {
  __shared__ __align__(16) float S[12288];
  int bi = blockIdx.x;
  int tid = threadIdx.x;
  if (bi >= 24) {
    int n = (bi - 24) * 512 + tid;
    if (n < N_NODES) cnt[n] = 0;
    return;
  }
  int chain = (bi >= 12);
  int kh = chain ? (bi - 12) : bi;
  int k = kh >> 2, h = kh & 3;
  const float* fck = (k == 0) ? fc1 : (k == 1) ? fc2 : fc3;
  fck += h * 128 * 64;
  const float* F = fcc + h * 192 * 64 + k * 64 * 64;
  int j = tid & 63, ig = tid >> 6;  // ig 0..7
  float o[4];
  if (!chain) {
    // ======== chain A: B1 -> WC0 / WC1 ========
    #pragma unroll
    for (int u = 0; u < 2; ++u) {
      ((float4*)S)[u * 512 + tid] = ((const float4*)F)[u * 512 + tid];
      ((float4*)(S + 4096))[u * 512 + tid] = ((const float4*)fck)[u * 512 + tid];
    }
    __syncthreads();
    // B1 = fckU @ F -> S[8192)
    #pragma unroll
    for (int rg = 0; rg < 2; ++rg) {
      int i0 = ig * 8 + rg * 4;
      mm4(S, 4096, 64, 0, i0, j, 64, o);
      S[8192 + (i0 + 0) * 64 + j] = o[0];
      S[8192 + (i0 + 1) * 64 + j] = o[1];
      S[8192 + (i0 + 2) * 64 + j] = o[2];
      S[8192 + (i0 + 3) * 64 + j] = o[3];
    }
    __syncthreads();
    // stage WfcU (rows 0..63, col slice h) -> S[4096)
    #pragma unroll
    for (int u = 0; u < 2; ++u) {
      int fi = u * 512 + tid;
      int i = fi >> 4, c4 = fi & 15;
      ((float4*)(S + 4096))[fi] = ((const float4*)(Wfc + i * 256 + h * 64))[c4];
    }
    __syncthreads();
    if (k == 0) {
      #pragma unroll
      for (int u = 0; u < 8; ++u) {
        int idx = u * 512 + tid;
        int i = idx >> 6, jj = idx & 63;
        bigWT[(h * 64 + jj) * 128 + i] = __float2half(S[4096 + idx]);
      }
    }
    // WC0 = WfcU @ B1 -> bigWT cols 0..63
    #pragma unroll
    for (int rg = 0; rg < 2; ++rg) {
      int i0 = ig * 8 + rg * 4;
      mm4(S, 4096, 64, 8192, i0, j, 64, o);
      int rb = ((k + 1) * 256 + h * 64 + j) * 128;
      bigWT[rb + i0 + 0] = __float2half(o[0]);
      bigWT[rb + i0 + 1] = __float2half(o[1]);
      bigWT[rb + i0 + 2] = __float2half(o[2]);
      bigWT[rb + i0 + 3] = __float2half(o[3]);
    }
    __syncthreads();
    // stage WfcL (rows 64..127) -> S[4096)
    #pragma unroll
    for (int u = 0; u < 2; ++u) {
      int fi = u * 512 + tid;
      int i = fi >> 4, c4 = fi & 15;
      ((float4*)(S + 4096))[fi] =
          ((const float4*)(Wfc + (64 + i) * 256 + h * 64))[c4];
    }
    __syncthreads();
    if (k == 0) {
      #pragma unroll
      for (int u = 0; u < 8; ++u) {
        int idx = u * 512 + tid;
        int i = idx >> 6, jj = idx & 63;
        bigWT[(h * 64 + jj) * 128 + 64 + i] = __float2half(S[4096 + idx]);
      }
    }
    // WC1 = WfcL @ B1 -> bigWT cols 64..127
    #pragma unroll
    for (int rg = 0; rg < 2; ++rg) {
      int i0 = ig * 8 + rg * 4;
      mm4(S, 4096, 64, 8192, i0, j, 64, o);
      int rb = ((k + 1) * 256 + h * 64 + j) * 128;
      bigWT[rb + 64 + i0 + 0] = __float2half(o[0]);
      bigWT[rb + 64 + i0 + 1] = __float2half(o[1]);
      bigWT[rb + 64 + i0 + 2] = __float2half(o[2]);
      bigWT[rb + 64 + i0 + 3] = __float2half(o[3]);
    }
    return;
  }
  // ======== chain B: B2 -> GB -> U ========
  #pragma unroll
  for (int u = 0; u < 2; ++u) {
    ((float4*)S)[u * 512 + tid] = ((const float4*)F)[u * 512 + tid];
    ((float4*)(S + 4096))[u * 512 + tid] =
        ((const float4*)(fck + 4096))[u * 512 + tid];
  }
  __syncthreads();
  // B2 = fckL @ F -> S[8192)
  #pragma unroll
  for (int rg = 0; rg < 2; ++rg) {
    int i0 = ig * 8 + rg * 4;
    mm4(S, 4096, 64, 0, i0, j, 64, o);
    S[8192 + (i0 + 0) * 64 + j] = o[0];
    S[8192 + (i0 + 1) * 64 + j] = o[1];
    S[8192 + (i0 + 2) * 64 + j] = o[2];
    S[8192 + (i0 + 3) * 64 + j] = o[3];
  }
  __syncthreads();
  // stage G_h -> S[0:2048), emb -> S[2048:3072)
  ((float4*)S)[tid] = ((const float4*)(G + h * 2048))[tid];
  if (tid < 256) ((float4*)(S + 2048))[tid] = ((const float4*)emb)[tid];
  __syncthreads();
  // GB = G @ B2 (32x64) -> S[3072)
  {
    int i0 = ig * 4;  // 8 igs x 4 rows = 32
    mm4(S, 0, 64, 8192, i0, j, 64, o);
    S[3072 + (i0 + 0) * 64 + j] = o[0];
    S[3072 + (i0 + 1) * 64 + j] = o[1];
    S[3072 + (i0 + 2) * 64 + j] = o[2];
    S[3072 + (i0 + 3) * 64 + j] = o[3];
  }
  __syncthreads();
  // U = emb @ GB (32x64, K=32) -> U16
  {
    int i0 = ig * 4;
    mm4(S, 2048, 32, 3072, i0, j, 32, o);
    int base = k * 8192 + h * 2048;
    U16[base + (i0 + 0) * 64 + j] = __float2half(o[0]);
    U16[base + (i0 + 1) * 64 + j] = __float2half(o[1]);
    U16[base + (i0 + 2) * 64 + j] = __float2half(o[2]);
    U16[base + (i0 + 3) * 64 + j] = __float2half(o[3]);
  }
}

// ---------------------------------------------------------------------------
// D2: FUSED gemm + edge. blocks 0..627 = MFMA gemm (64x256 region tiles,
// LDS-staged epilogue, fp32->fp16 A-convert in-register); blocks 628..1252 =
// edge pass (dist->bucket, CSR scatter). Independent work; edge's latency
// stalls hide under gemm's MFMA occupancy.
// record uint4: x = s | it0<<16 ; y = it1 | it2<<16 ;
//               z = it3 | i1<<16 | q2_0<<21 | q__0<<26 ;
//               w = (q2_h | q__h<<5) << ((h-1)*10)  for h=1..3
// ---------------------------------------------------------------------------
#define EROW 264  // epilogue LDS row stride in halves

__global__ __launch_bounds__(256) void gemm_edge_kernel(
    const float* __restrict__ feat, const __half* __restrict__ bigWT,
    __half* __restrict__ qall, const float* __restrict__ pos,
    const int* __restrict__ src, const int* __restrict__ dst,
    const int* __restrict__ inter, const float* __restrict__ boundaries,
    int* __restrict__ cnt, uint4* __restrict__ ebuf) {
  __shared__ __align__(16) __half Esm[4][16][EROW];
  __shared__ float Sb[48];
  int bi = blockIdx.x;
  int tid = threadIdx.x;
  if (bi >= 628) {
    // ---- edge path ----
    if (tid < NBOUND) Sb[tid + 1] = boundaries[tid];
    if (tid == NBOUND) { Sb[0] = -INFINITY; Sb[32] = INFINITY; }
    __syncthreads();
    int e = (bi - 628) * 256 + tid;  // 625*256 == E exactly
    int s = src[e], t = dst[e];
    int4 iv = *(const int4*)&inter[e * 4];
    int itarr[4] = {iv.x, iv.y, iv.z, iv.w};
    float sx = pos[s * 3], sy = pos[s * 3 + 1], sz = pos[s * 3 + 2];
    float tx = pos[t * 3], ty = pos[t * 3 + 1], tz = pos[t * 3 + 2];
    float dx = tx - sx, dy = ty - sy, dz = tz - sz;
    float dist1 = sqrtf(dx * dx + dy * dy + dz * dz);
    unsigned i1 = (unsigned)didx(Sb, dist1);
    unsigned w3 = 0, q20 = 0, q_0 = 0;
    #pragma unroll
    for (int hh = 0; hh < 4; ++hh) {
      int it = itarr[hh];
      float ix = pos[it * 3], iy = pos[it * 3 + 1], iz = pos[it * 3 + 2];
      float ax = tx - ix, ay = ty - iy, az = tz - iz;
      float dist2 = sqrtf(ax * ax + ay * ay + az * az);
      float bx = sx - ix, by = sy - iy, bz = sz - iz;
      float dist_ = sqrtf(bx * bx + by * by + bz * bz);
      unsigned idx2 = (unsigned)didx(Sb, dist2);
      unsigned idx_ = (unsigned)didx(Sb, dist_);
      if (hh == 0) { q20 = idx2; q_0 = idx_; }
      else w3 |= (idx2 | (idx_ << 5)) << ((hh - 1) * 10);
    }
    uint4 rec;
    rec.x = (unsigned)s | ((unsigned)itarr[0] << 16);
    rec.y = (unsigned)itarr[1] | ((unsigned)itarr[2] << 16);
    rec.z = (unsigned)itarr[3] | (i1 << 16) | (q20 << 21) | (q_0 << 26);
    rec.w = w3;
    int p = atomicAdd(&cnt[t], 1);
    if (p < SLOTS) ebuf[t * SLOTS + p] = rec;
    return;
  }
  // ---- gemm path ----
  int bx = bi % 157, by = bi / 157;  // by = region 0..3
  int wv = tid >> 6, l = tid & 63;
  int m0 = bx * 64 + wv * 16;
  int n0 = by * 256;
  int lm = l & 15, lk = (l >> 4) * 8;
  int arow = m0 + lm;
  if (arow >= N_NODES) arow = N_NODES - 1;
  const float* fp = feat + arow * 128 + lk;
  const _Float16* bp = (const _Float16*)bigWT + lk;
  half8 a[4];
  #pragma unroll
  for (int kt = 0; kt < 4; ++kt) {
    float4 u0 = *(const float4*)(fp + kt * 32);
    float4 u1 = *(const float4*)(fp + kt * 32 + 4);
    half8 t;
    t[0] = (_Float16)u0.x; t[1] = (_Float16)u0.y;
    t[2] = (_Float16)u0.z; t[3] = (_Float16)u0.w;
    t[4] = (_Float16)u1.x; t[5] = (_Float16)u1.y;
    t[6] = (_Float16)u1.z; t[7] = (_Float16)u1.w;
    a[kt] = t;
  }
  #pragma unroll
  for (int nt = 0; nt < 16; ++nt) {
    floatx4 acc = (floatx4){0.f, 0.f, 0.f, 0.f};
    #pragma unroll
    for (int kt = 0; kt < 4; ++kt) {
      half8 b = *(const half8*)(bp + (n0 + nt * 16 + lm) * 128 + kt * 32);
      acc = __builtin_amdgcn_mfma_f32_16x16x32_f16(a[kt], b, acc, 0, 0, 0);
    }
    int dd = nt * 16 + lm;  // col within region, 0..255
    int o = (by == 0) ? ((dd & 63) * 4 + (dd >> 6)) : dd;
    #pragma unroll
    for (int r4 = 0; r4 < 4; ++r4)
      Esm[wv][(l >> 4) * 4 + r4][o] = __float2half(acc[r4]);
  }
  __syncthreads();
  int row = l >> 2;       // 0..15
  int j0 = (l & 3) * 64;  // 0,64,128,192
  int m = m0 + row;
  if (m < N_NODES) {
    #pragma unroll
    for (int u = 0; u < 8; ++u) {
      uint4 v = *(const uint4*)&Esm[wv][row][j0 + u * 8];
      *(uint4*)&qall[m * QREC + by * 256 + j0 + u * 8] = v;
    }
  }
}

// ---------------------------------------------------------------------------
// D3: FUSED score + aggregation. Block per node, 4 waves stride the node's
// CSR bucket with FOUR edges in flight per wave (deg<=64 -> <=4 iters).
// q3[dst] loaded once per block. Max-free softmax (|score| <= ~15).
// ---------------------------------------------------------------------------
__device__ __forceinline__ float dpp_row_sum16(float v) {
  int x;
  x = __builtin_amdgcn_update_dpp(0, __float_as_int(v), 0x128, 0xf, 0xf, true);
  v += __int_as_float(x);
  x = __builtin_amdgcn_update_dpp(0, __float_as_int(v), 0x124, 0xf, 0xf, true);
  v += __int_as_float(x);
  x = __builtin_amdgcn_update_dpp(0, __float_as_int(v), 0x122, 0xf, 0xf, true);
  v += __int_as_float(x);
  x = __builtin_amdgcn_update_dpp(0, __float_as_int(v), 0x121, 0xf, 0xf, true);
  v += __int_as_float(x);
  return v;
}

union H4u { uint2 u; __half2 h[2]; };

__device__ __forceinline__ float tanh_dot(H4u A, H4u B, H4u C, H4u X, H4u Y,
                                          H4u Z, float4 a4) {
  __half2 z0 = __hadd2(__hadd2(A.h[0], B.h[0]), __hadd2(C.h[0], X.h[0]));
  z0 = __hadd2(z0, __hadd2(Y.h[0], Z.h[0]));
  __half2 z1 = __hadd2(__hadd2(A.h[1], B.h[1]), __hadd2(C.h[1], X.h[1]));
  z1 = __hadd2(z1, __hadd2(Y.h[1], Z.h[1]));
  float2 f0 = __half22float2(z0);
  float2 f1 = __half22float2(z1);
  const float K = 2.885390082f;  // 2*log2(e)
  float p0 = __builtin_amdgcn_exp2f(f0.x * K);
  float p1 = __builtin_amdgcn_exp2f(f0.y * K);
  float p2 = __builtin_amdgcn_exp2f(f1.x * K);
  float p3 = __builtin_amdgcn_exp2f(f1.y * K);
  float r0 = __builtin_amdgcn_rcpf(p0 + 1.0f);
  float r1 = __builtin_amdgcn_rcpf(p1 + 1.0f);
  float r2 = __builtin_amdgcn_rcpf(p2 + 1.0f);
  float r3 = __builtin_amdgcn_rcpf(p3 + 1.0f);
  float dot = a4.x * r0;
  dot = fmaf(a4.y, r1, dot);
  dot = fmaf(a4.z, r2, dot);
  dot = fmaf(a4.w, r3, dot);
  float asum = (a4.x + a4.y) + (a4.z + a4.w);
  return fmaf(-2.0f, dot, asum);
}

__device__ __forceinline__ float4 h4_to_f4(uint2 u) {
  union { uint2 ui; __half2 h[2]; } cc;
  cc.ui = u;
  float2 a = __half22float2(cc.h[0]);
  float2 b = __half22float2(cc.h[1]);
  return make_float4(a.x, a.y, b.x, b.y);
}

__device__ __forceinline__ void dec_rec(uint4 r, int h, int* s, int* it,
                                        unsigned* i1, unsigned* q2,
                                        unsigned* q_) {
  *s = (int)(r.x & 0xffff);
  *it = (h == 0) ? (int)(r.x >> 16)
      : (h == 1) ? (int)(r.y & 0xffff)
      : (h == 2) ? (int)(r.y >> 16) : (int)(r.z & 0xffff);
  *i1 = (r.z >> 16) & 31;
  if (h == 0) {
    *q2 = (r.z >> 21) & 31;
    *q_ = (r.z >> 26) & 31;
  } else {
    unsigned f = r.w >> ((h - 1) * 10);
    *q2 = f & 31;
    *q_ = (f >> 5) & 31;
  }
}

__device__ __forceinline__ void gather_edge(
    const __half* __restrict__ qall, const __half* __restrict__ U16, int h,
    int c, int lane, int s, int it, unsigned i1, unsigned q2, unsigned q_,
    H4u* A, H4u* B, H4u* X, H4u* Y, H4u* Z, uint2* hr) {
  A->u = *(const uint2*)(qall + s * QREC + 256 + h * 64 + c * 4);
  B->u = *(const uint2*)(qall + it * QREC + 512 + h * 64 + c * 4);
  X->u = *(const uint2*)(U16 + (h * 32 + (int)i1) * 64 + c * 4);
  Y->u = *(const uint2*)(U16 + 8192 + (h * 32 + (int)q2) * 64 + c * 4);
  Z->u = *(const uint2*)(U16 + 16384 + (h * 32 + (int)q_) * 64 + c * 4);
  *hr = *(const uint2*)(qall + s * QREC + lane * 4);  // h[d=lane][4 heads]
}

__global__ __launch_bounds__(256) void score_agg_kernel(
    const int* __restrict__ cnt, const uint4* __restrict__ ebuf,
    const __half* __restrict__ qall, const __half* __restrict__ U16,
    const float* __restrict__ aout, float* __restrict__ out) {
  __shared__ uint4 recs[SLOTS];
  __shared__ float4 sm_num[4][64];
  __shared__ float4 sm_den[4];
  int tid = threadIdx.x;
  int w = tid >> 6, lane = tid & 63;
  int h = lane >> 4, c = lane & 15;
  int n = blockIdx.x;
  int deg = cnt[n];
  if (deg > SLOTS) deg = SLOTS;
  if (tid < deg) recs[tid] = ebuf[n * SLOTS + tid];
  H4u C;
  C.u = *(const uint2*)(qall + n * QREC + 768 + h * 64 + c * 4);
  const float4 a4 = *((const float4*)(aout + h * 64) + c);
  __syncthreads();
  float4 num = make_float4(0.f, 0.f, 0.f, 0.f);
  float4 den = make_float4(0.f, 0.f, 0.f, 0.f);
  for (int i = w; i < deg; i += 16) {
    // 4 edges in flight: i, i+4, i+8, i+12 (validity is wave-uniform)
    int val[4];
    uint4 r[4];
    #pragma unroll
    for (int u = 0; u < 4; ++u) {
      int idx = i + 4 * u;
      val[u] = (idx < deg);
      r[u] = recs[val[u] ? idx : i];
    }
    int s[4], it[4];
    unsigned i1[4], q2[4], q_[4];
    #pragma unroll
    for (int u = 0; u < 4; ++u)
      dec_rec(r[u], h, &s[u], &it[u], &i1[u], &q2[u], &q_[u]);
    H4u A[4], B[4], X[4], Y[4], Z[4];
    uint2 hr[4];
    #pragma unroll
    for (int u = 0; u < 4; ++u)
      gather_edge(qall, U16, h, c, lane, s[u], it[u], i1[u], q2[u], q_[u],
                  &A[u], &B[u], &X[u], &Y[u], &Z[u], &hr[u]);
    float v[4];
    #pragma unroll
    for (int u = 0; u < 4; ++u)
      v[u] = tanh_dot(A[u], B[u], C, X[u], Y[u], Z[u], a4);
    #pragma unroll
    for (int u = 0; u < 4; ++u) v[u] = dpp_row_sum16(v[u]);
    #pragma unroll
    for (int u = 0; u < 4; ++u) {
      float ex = val[u] ? __expf(v[u]) : 0.f;
      float e0 = __shfl(ex, 0), e1 = __shfl(ex, 16);
      float e2 = __shfl(ex, 32), e3 = __shfl(ex, 48);
      float4 hv = h4_to_f4(hr[u]);
      num.x += e0 * hv.x;
      num.y += e1 * hv.y;
      num.z += e2 * hv.z;
      num.w += e3 * hv.w;
      den.x += e0; den.y += e1; den.z += e2; den.w += e3;
    }
  }
  sm_num[w][lane] = num;
  if (lane == 0) sm_den[w] = den;
  __syncthreads();
  if (tid < 64) {
    float4 n0 = sm_num[0][tid], n1 = sm_num[1][tid];
    float4 n2 = sm_num[2][tid], n3 = sm_num[3][tid];
    float4 d0 = sm_den[0], d1 = sm_den[1], d2 = sm_den[2], d3 = sm_den[3];
    float4 ns = make_float4(n0.x + n1.x + n2.x + n3.x, n0.y + n1.y + n2.y + n3.y,
                            n0.z + n1.z + n2.z + n3.z, n0.w + n1.w + n2.w + n3.w);
    float4 ds = make_float4(d0.x + d1.x + d2.x + d3.x, d0.y + d1.y + d2.y + d3.y,
                            d0.z + d1.z + d2.z + d3.z, d0.w + d1.w + d2.w + d3.w);
    float r = 0.f;
    if (deg > 0)
      r = 0.25f * (ns.x / ds.x + ns.y / ds.y + ns.z / ds.z + ns.w / ds.w);
    out[n * 64 + tid] = r;
  }
}

// ---------------------------------------------------------------------------
extern "C" void kernel_launch(void* const* d_in, const int* in_sizes, int n_in,
                              void* d_out, int out_size, void* d_ws,
                              size_t ws_size, hipStream_t stream) {
  const float* feat = (const float*)d_in[0];
  const float* loc = (const float*)d_in[1];
  const int* src = (const int*)d_in[2];
  const int* dst = (const int*)d_in[3];
  const int* inter = (const int*)d_in[4];
  const float* Wfc = (const float*)d_in[5];
  const float* emb = (const float*)d_in[6];
  const float* G = (const float*)d_in[7];
  const float* fc1 = (const float*)d_in[8];
  const float* fc2 = (const float*)d_in[9];
  const float* fc3 = (const float*)d_in[10];
  const float* fcc = (const float*)d_in[11];
  const float* aout = (const float*)d_in[12];
  const float* bnd = (const float*)d_in[13];
  float* out = (float*)d_out;

  __half* qall = (__half*)d_ws;           // N*1024 halfs (20.48 MB)
  __half* bigWT = qall + N_NODES * QREC;  // 1024*128 halfs
  __half* U16 = bigWT + 1024 * 128;       // 3*4*2048 halfs
  uint4* ebuf = (uint4*)(U16 + 3 * H * 2048);  // N*SLOTS uint4 (10.24 MB)
  int* cnt = (int*)(ebuf + N_NODES * SLOTS);   // N ints

  prep_kernel<<<44, 512, 0, stream>>>(fc1, fc2, fc3, fcc, Wfc, G, emb, bigWT,
                                      U16, cnt);
  gemm_edge_kernel<<<1253, 256, 0, stream>>>(feat, bigWT, qall, loc, src, dst,
                                             inter, bnd, cnt, ebuf);
  score_agg_kernel<<<N_NODES, 256, 0, stream>>>(cnt, ebuf, qall, U16, aout,
                                                out);
}

// Round 5
// 174.408 us; speedup vs baseline: 1.3583x; 1.0571x over previous
//
#include <hip/hip_runtime.h>
#include <hip/hip_fp16.h>
#include <math.h>

#define N_NODES 10000
#define E_EDGES 160000
#define DMODEL 64
#define H 4
#define NBOUND 31
#define SLOTS 64  // fixed per-node CSR bucket; P(deg>64)<1e-11 for multinomial(16)
// qall record per node (fp16, 1024 halves):
//  [0:256)    h  d-major: offset d*4 + head   (one 8B load = all 4 heads at d)
//  [256:512)  q1: 256 + head*64 + d
//  [512:768)  q2: 512 + head*64 + d
//  [768:1024) q3: 768 + head*64 + d
#define QREC 1024

typedef _Float16 half8 __attribute__((ext_vector_type(8)));
typedef float floatx4 __attribute__((ext_vector_type(4)));

// ---------------------------------------------------------------------------
// LDS 64-wide microtile helper: o[r] = sum_t A[i0+r][t] * B[t][j].
// ---------------------------------------------------------------------------
__device__ __forceinline__ void mm4(const float* __restrict__ S, int aoff,
                                    int astride, int boff, int i0, int j,
                                    int Kdim, float o[4]) {
  float a0 = 0.f, a1 = 0.f, a2 = 0.f, a3 = 0.f;
  for (int t4 = 0; t4 < (Kdim >> 2); ++t4) {
    float4 f0 = *(const float4*)&S[aoff + (i0 + 0) * astride + t4 * 4];
    float4 f1 = *(const float4*)&S[aoff + (i0 + 1) * astride + t4 * 4];
    float4 f2 = *(const float4*)&S[aoff + (i0 + 2) * astride + t4 * 4];
    float4 f3 = *(const float4*)&S[aoff + (i0 + 3) * astride + t4 * 4];
    float b0 = S[boff + (t4 * 4 + 0) * 64 + j];
    float b1 = S[boff + (t4 * 4 + 1) * 64 + j];
    float b2 = S[boff + (t4 * 4 + 2) * 64 + j];
    float b3 = S[boff + (t4 * 4 + 3) * 64 + j];
    a0 += f0.x * b0 + f0.y * b1 + f0.z * b2 + f0.w * b3;
    a1 += f1.x * b0 + f1.y * b1 + f1.z * b2 + f1.w * b3;
    a2 += f2.x * b0 + f2.y * b1 + f2.z * b2 + f2.w * b3;
    a3 += f3.x * b0 + f3.y * b1 + f3.z * b2 + f3.w * b3;
  }
  o[0] = a0; o[1] = a1; o[2] = a2; o[3] = a3;
}

__device__ __forceinline__ int didx(const float* __restrict__ bnd2, float d) {
  int g = (int)(d * 10.0f);
  g = (g < 0) ? 0 : ((g > 31) ? 31 : g);
  g += (bnd2[g + 1] < d) ? 1 : 0;
  g -= (bnd2[g] >= d) ? 1 : 0;
  return g;
}

// ---------------------------------------------------------------------------
// D1: prep. blocks 0..11 chain A (B1->WC0/WC1 -> bigWT), 12..23 chain B
// (B2->GB->U -> U16), 24..43 zero cnt (replaces memset dispatch).
// ---------------------------------------------------------------------------
__global__ __launch_bounds__(512) void prep_kernel(
    const float* __restrict__ fc1, const float* __restrict__ fc2,
    const float* __restrict__ fc3, const float* __restrict__ fcc,
    const float* __restrict__ Wfc, const float* __restrict__ G,
    const float* __restrict__ emb, __half* __restrict__ bigWT,
    __half* __restrict__ U16, int* __restrict__ cnt) {
  __shared__ __align__(16) float S[12288];
  int bi = blockIdx.x;
  int tid = threadIdx.x;
  if (bi >= 24) {
    int n = (bi - 24) * 512 + tid;
    if (n < N_NODES) cnt[n] = 0;
    return;
  }
  int chain = (bi >= 12);
  int kh = chain ? (bi - 12) : bi;
  int k = kh >> 2, h = kh & 3;
  const float* fck = (k == 0) ? fc1 : (k == 1) ? fc2 : fc3;
  fck += h * 128 * 64;
  const float* F = fcc + h * 192 * 64 + k * 64 * 64;
  int j = tid & 63, ig = tid >> 6;  // ig 0..7
  float o[4];
  if (!chain) {
    // ======== chain A: B1 -> WC0 / WC1 ========
    #pragma unroll
    for (int u = 0; u < 2; ++u) {
      ((float4*)S)[u * 512 + tid] = ((const float4*)F)[u * 512 + tid];
      ((float4*)(S + 4096))[u * 512 + tid] = ((const float4*)fck)[u * 512 + tid];
    }
    __syncthreads();
    // B1 = fckU @ F -> S[8192)
    #pragma unroll
    for (int rg = 0; rg < 2; ++rg) {
      int i0 = ig * 8 + rg * 4;
      mm4(S, 4096, 64, 0, i0, j, 64, o);
      S[8192 + (i0 + 0) * 64 + j] = o[0];
      S[8192 + (i0 + 1) * 64 + j] = o[1];
      S[8192 + (i0 + 2) * 64 + j] = o[2];
      S[8192 + (i0 + 3) * 64 + j] = o[3];
    }
    __syncthreads();
    // stage WfcU (rows 0..63, col slice h) -> S[4096)
    #pragma unroll
    for (int u = 0; u < 2; ++u) {
      int fi = u * 512 + tid;
      int i = fi >> 4, c4 = fi & 15;
      ((float4*)(S + 4096))[fi] = ((const float4*)(Wfc + i * 256 + h * 64))[c4];
    }
    __syncthreads();
    if (k == 0) {
      #pragma unroll
      for (int u = 0; u < 8; ++u) {
        int idx = u * 512 + tid;
        int i = idx >> 6, jj = idx & 63;
        bigWT[(h * 64 + jj) * 128 + i] = __float2half(S[4096 + idx]);
      }
    }
    // WC0 = WfcU @ B1 -> bigWT cols 0..63
    #pragma unroll
    for (int rg = 0; rg < 2; ++rg) {
      int i0 = ig * 8 + rg * 4;
      mm4(S, 4096, 64, 8192, i0, j, 64, o);
      int rb = ((k + 1) * 256 + h * 64 + j) * 128;
      bigWT[rb + i0 + 0] = __float2half(o[0]);
      bigWT[rb + i0 + 1] = __float2half(o[1]);
      bigWT[rb + i0 + 2] = __float2half(o[2]);
      bigWT[rb + i0 + 3] = __float2half(o[3]);
    }
    __syncthreads();
    // stage WfcL (rows 64..127) -> S[4096)
    #pragma unroll
    for (int u = 0; u < 2; ++u) {
      int fi = u * 512 + tid;
      int i = fi >> 4, c4 = fi & 15;
      ((float4*)(S + 4096))[fi] =
          ((const float4*)(Wfc + (64 + i) * 256 + h * 64))[c4];
    }
    __syncthreads();
    if (k == 0) {
      #pragma unroll
      for (int u = 0; u < 8; ++u) {
        int idx = u * 512 + tid;
        int i = idx >> 6, jj = idx & 63;
        bigWT[(h * 64 + jj) * 128 + 64 + i] = __float2half(S[4096 + idx]);
      }
    }
    // WC1 = WfcL @ B1 -> bigWT cols 64..127
    #pragma unroll
    for (int rg = 0; rg < 2; ++rg) {
      int i0 = ig * 8 + rg * 4;
      mm4(S, 4096, 64, 8192, i0, j, 64, o);
      int rb = ((k + 1) * 256 + h * 64 + j) * 128;
      bigWT[rb + 64 + i0 + 0] = __float2half(o[0]);
      bigWT[rb + 64 + i0 + 1] = __float2half(o[1]);
      bigWT[rb + 64 + i0 + 2] = __float2half(o[2]);
      bigWT[rb + 64 + i0 + 3] = __float2half(o[3]);
    }
    return;
  }
  // ======== chain B: B2 -> GB -> U ========
  #pragma unroll
  for (int u = 0; u < 2; ++u) {
    ((float4*)S)[u * 512 + tid] = ((const float4*)F)[u * 512 + tid];
    ((float4*)(S + 4096))[u * 512 + tid] =
        ((const float4*)(fck + 4096))[u * 512 + tid];
  }
  __syncthreads();
  // B2 = fckL @ F -> S[8192)
  #pragma unroll
  for (int rg = 0; rg < 2; ++rg) {
    int i0 = ig * 8 + rg * 4;
    mm4(S, 4096, 64, 0, i0, j, 64, o);
    S[8192 + (i0 + 0) * 64 + j] = o[0];
    S[8192 + (i0 + 1) * 64 + j] = o[1];
    S[8192 + (i0 + 2) * 64 + j] = o[2];
    S[8192 + (i0 + 3) * 64 + j] = o[3];
  }
  __syncthreads();
  // stage G_h -> S[0:2048), emb -> S[2048:3072)
  ((float4*)S)[tid] = ((const float4*)(G + h * 2048))[tid];
  if (tid < 256) ((float4*)(S + 2048))[tid] = ((const float4*)emb)[tid];
  __syncthreads();
  // GB = G @ B2 (32x64) -> S[3072)
  {
    int i0 = ig * 4;  // 8 igs x 4 rows = 32
    mm4(S, 0, 64, 8192, i0, j, 64, o);
    S[3072 + (i0 + 0) * 64 + j] = o[0];
    S[3072 + (i0 + 1) * 64 + j] = o[1];
    S[3072 + (i0 + 2) * 64 + j] = o[2];
    S[3072 + (i0 + 3) * 64 + j] = o[3];
  }
  __syncthreads();
  // U = emb @ GB (32x64, K=32) -> U16
  {
    int i0 = ig * 4;
    mm4(S, 2048, 32, 3072, i0, j, 32, o);
    int base = k * 8192 + h * 2048;
    U16[base + (i0 + 0) * 64 + j] = __float2half(o[0]);
    U16[base + (i0 + 1) * 64 + j] = __float2half(o[1]);
    U16[base + (i0 + 2) * 64 + j] = __float2half(o[2]);
    U16[base + (i0 + 3) * 64 + j] = __float2half(o[3]);
  }
}

// ---------------------------------------------------------------------------
// D2: FUSED gemm + edge. blocks 0..627 = MFMA gemm (64x256 region tiles,
// LDS-staged epilogue, fp32->fp16 A-convert in-register); blocks 628..1252 =
// edge pass (dist->bucket, CSR scatter). Independent work; edge's latency
// stalls hide under gemm's MFMA occupancy.
// record uint4: x = s | it0<<16 ; y = it1 | it2<<16 ;
//               z = it3 | i1<<16 | q2_0<<21 | q__0<<26 ;
//               w = (q2_h | q__h<<5) << ((h-1)*10)  for h=1..3
// ---------------------------------------------------------------------------
#define EROW 264  // epilogue LDS row stride in halves

__global__ __launch_bounds__(256) void gemm_edge_kernel(
    const float* __restrict__ feat, const __half* __restrict__ bigWT,
    __half* __restrict__ qall, const float* __restrict__ pos,
    const int* __restrict__ src, const int* __restrict__ dst,
    const int* __restrict__ inter, const float* __restrict__ boundaries,
    int* __restrict__ cnt, uint4* __restrict__ ebuf) {
  __shared__ __align__(16) __half Esm[4][16][EROW];
  __shared__ float Sb[48];
  int bi = blockIdx.x;
  int tid = threadIdx.x;
  if (bi >= 628) {
    // ---- edge path ----
    if (tid < NBOUND) Sb[tid + 1] = boundaries[tid];
    if (tid == NBOUND) { Sb[0] = -INFINITY; Sb[32] = INFINITY; }
    __syncthreads();
    int e = (bi - 628) * 256 + tid;  // 625*256 == E exactly
    int s = src[e], t = dst[e];
    int4 iv = *(const int4*)&inter[e * 4];
    int itarr[4] = {iv.x, iv.y, iv.z, iv.w};
    float sx = pos[s * 3], sy = pos[s * 3 + 1], sz = pos[s * 3 + 2];
    float tx = pos[t * 3], ty = pos[t * 3 + 1], tz = pos[t * 3 + 2];
    float dx = tx - sx, dy = ty - sy, dz = tz - sz;
    float dist1 = sqrtf(dx * dx + dy * dy + dz * dz);
    unsigned i1 = (unsigned)didx(Sb, dist1);
    unsigned w3 = 0, q20 = 0, q_0 = 0;
    #pragma unroll
    for (int hh = 0; hh < 4; ++hh) {
      int it = itarr[hh];
      float ix = pos[it * 3], iy = pos[it * 3 + 1], iz = pos[it * 3 + 2];
      float ax = tx - ix, ay = ty - iy, az = tz - iz;
      float dist2 = sqrtf(ax * ax + ay * ay + az * az);
      float bx = sx - ix, by = sy - iy, bz = sz - iz;
      float dist_ = sqrtf(bx * bx + by * by + bz * bz);
      unsigned idx2 = (unsigned)didx(Sb, dist2);
      unsigned idx_ = (unsigned)didx(Sb, dist_);
      if (hh == 0) { q20 = idx2; q_0 = idx_; }
      else w3 |= (idx2 | (idx_ << 5)) << ((hh - 1) * 10);
    }
    uint4 rec;
    rec.x = (unsigned)s | ((unsigned)itarr[0] << 16);
    rec.y = (unsigned)itarr[1] | ((unsigned)itarr[2] << 16);
    rec.z = (unsigned)itarr[3] | (i1 << 16) | (q20 << 21) | (q_0 << 26);
    rec.w = w3;
    int p = atomicAdd(&cnt[t], 1);
    if (p < SLOTS) ebuf[t * SLOTS + p] = rec;
    return;
  }
  // ---- gemm path ----
  int bx = bi % 157, by = bi / 157;  // by = region 0..3
  int wv = tid >> 6, l = tid & 63;
  int m0 = bx * 64 + wv * 16;
  int n0 = by * 256;
  int lm = l & 15, lk = (l >> 4) * 8;
  int arow = m0 + lm;
  if (arow >= N_NODES) arow = N_NODES - 1;
  const float* fp = feat + arow * 128 + lk;
  const _Float16* bp = (const _Float16*)bigWT + lk;
  half8 a[4];
  #pragma unroll
  for (int kt = 0; kt < 4; ++kt) {
    float4 u0 = *(const float4*)(fp + kt * 32);
    float4 u1 = *(const float4*)(fp + kt * 32 + 4);
    half8 t;
    t[0] = (_Float16)u0.x; t[1] = (_Float16)u0.y;
    t[2] = (_Float16)u0.z; t[3] = (_Float16)u0.w;
    t[4] = (_Float16)u1.x; t[5] = (_Float16)u1.y;
    t[6] = (_Float16)u1.z; t[7] = (_Float16)u1.w;
    a[kt] = t;
  }
  #pragma unroll
  for (int nt = 0; nt < 16; ++nt) {
    floatx4 acc = (floatx4){0.f, 0.f, 0.f, 0.f};
    #pragma unroll
    for (int kt = 0; kt < 4; ++kt) {
      half8 b = *(const half8*)(bp + (n0 + nt * 16 + lm) * 128 + kt * 32);
      acc = __builtin_amdgcn_mfma_f32_16x16x32_f16(a[kt], b, acc, 0, 0, 0);
    }
    int dd = nt * 16 + lm;  // col within region, 0..255
    int o = (by == 0) ? ((dd & 63) * 4 + (dd >> 6)) : dd;
    #pragma unroll
    for (int r4 = 0; r4 < 4; ++r4)
      Esm[wv][(l >> 4) * 4 + r4][o] = __float2half(acc[r4]);
  }
  __syncthreads();
  int row = l >> 2;       // 0..15
  int j0 = (l & 3) * 64;  // 0,64,128,192
  int m = m0 + row;
  if (m < N_NODES) {
    #pragma unroll
    for (int u = 0; u < 8; ++u) {
      uint4 v = *(const uint4*)&Esm[wv][row][j0 + u * 8];
      *(uint4*)&qall[m * QREC + by * 256 + j0 + u * 8] = v;
    }
  }
}

// ---------------------------------------------------------------------------
// D3: FUSED score + aggregation. Block per node, 4 waves stride the node's
// CSR bucket, TWO edges in flight per wave (proven optimal depth; 4-deep
// regressed -- overflows useful outstanding-load window). q3[dst] loaded
// once per block. Max-free softmax (|score| <= ~15).
// ---------------------------------------------------------------------------
__device__ __forceinline__ float dpp_row_sum16(float v) {
  int x;
  x = __builtin_amdgcn_update_dpp(0, __float_as_int(v), 0x128, 0xf, 0xf, true);
  v += __int_as_float(x);
  x = __builtin_amdgcn_update_dpp(0, __float_as_int(v), 0x124, 0xf, 0xf, true);
  v += __int_as_float(x);
  x = __builtin_amdgcn_update_dpp(0, __float_as_int(v), 0x122, 0xf, 0xf, true);
  v += __int_as_float(x);
  x = __builtin_amdgcn_update_dpp(0, __float_as_int(v), 0x121, 0xf, 0xf, true);
  v += __int_as_float(x);
  return v;
}

union H4u { uint2 u; __half2 h[2]; };

__device__ __forceinline__ float tanh_dot(H4u A, H4u B, H4u C, H4u X, H4u Y,
                                          H4u Z, float4 a4) {
  __half2 z0 = __hadd2(__hadd2(A.h[0], B.h[0]), __hadd2(C.h[0], X.h[0]));
  z0 = __hadd2(z0, __hadd2(Y.h[0], Z.h[0]));
  __half2 z1 = __hadd2(__hadd2(A.h[1], B.h[1]), __hadd2(C.h[1], X.h[1]));
  z1 = __hadd2(z1, __hadd2(Y.h[1], Z.h[1]));
  float2 f0 = __half22float2(z0);
  float2 f1 = __half22float2(z1);
  const float K = 2.885390082f;  // 2*log2(e)
  float p0 = __builtin_amdgcn_exp2f(f0.x * K);
  float p1 = __builtin_amdgcn_exp2f(f0.y * K);
  float p2 = __builtin_amdgcn_exp2f(f1.x * K);
  float p3 = __builtin_amdgcn_exp2f(f1.y * K);
  float r0 = __builtin_amdgcn_rcpf(p0 + 1.0f);
  float r1 = __builtin_amdgcn_rcpf(p1 + 1.0f);
  float r2 = __builtin_amdgcn_rcpf(p2 + 1.0f);
  float r3 = __builtin_amdgcn_rcpf(p3 + 1.0f);
  float dot = a4.x * r0;
  dot = fmaf(a4.y, r1, dot);
  dot = fmaf(a4.z, r2, dot);
  dot = fmaf(a4.w, r3, dot);
  float asum = (a4.x + a4.y) + (a4.z + a4.w);
  return fmaf(-2.0f, dot, asum);
}

__device__ __forceinline__ float4 h4_to_f4(uint2 u) {
  union { uint2 ui; __half2 h[2]; } cc;
  cc.ui = u;
  float2 a = __half22float2(cc.h[0]);
  float2 b = __half22float2(cc.h[1]);
  return make_float4(a.x, a.y, b.x, b.y);
}

__device__ __forceinline__ void dec_rec(uint4 r, int h, int* s, int* it,
                                        unsigned* i1, unsigned* q2,
                                        unsigned* q_) {
  *s = (int)(r.x & 0xffff);
  *it = (h == 0) ? (int)(r.x >> 16)
      : (h == 1) ? (int)(r.y & 0xffff)
      : (h == 2) ? (int)(r.y >> 16) : (int)(r.z & 0xffff);
  *i1 = (r.z >> 16) & 31;
  if (h == 0) {
    *q2 = (r.z >> 21) & 31;
    *q_ = (r.z >> 26) & 31;
  } else {
    unsigned f = r.w >> ((h - 1) * 10);
    *q2 = f & 31;
    *q_ = (f >> 5) & 31;
  }
}

__device__ __forceinline__ void gather_edge(
    const __half* __restrict__ qall, const __half* __restrict__ U16, int h,
    int c, int lane, int s, int it, unsigned i1, unsigned q2, unsigned q_,
    H4u* A, H4u* B, H4u* X, H4u* Y, H4u* Z, uint2* hr) {
  A->u = *(const uint2*)(qall + s * QREC + 256 + h * 64 + c * 4);
  B->u = *(const uint2*)(qall + it * QREC + 512 + h * 64 + c * 4);
  X->u = *(const uint2*)(U16 + (h * 32 + (int)i1) * 64 + c * 4);
  Y->u = *(const uint2*)(U16 + 8192 + (h * 32 + (int)q2) * 64 + c * 4);
  Z->u = *(const uint2*)(U16 + 16384 + (h * 32 + (int)q_) * 64 + c * 4);
  *hr = *(const uint2*)(qall + s * QREC + lane * 4);  // h[d=lane][4 heads]
}

__global__ __launch_bounds__(256) void score_agg_kernel(
    const int* __restrict__ cnt, const uint4* __restrict__ ebuf,
    const __half* __restrict__ qall, const __half* __restrict__ U16,
    const float* __restrict__ aout, float* __restrict__ out) {
  __shared__ uint4 recs[SLOTS];
  __shared__ float4 sm_num[4][64];
  __shared__ float4 sm_den[4];
  int tid = threadIdx.x;
  int w = tid >> 6, lane = tid & 63;
  int h = lane >> 4, c = lane & 15;
  int n = blockIdx.x;
  int deg = cnt[n];
  if (deg > SLOTS) deg = SLOTS;
  if (tid < deg) recs[tid] = ebuf[n * SLOTS + tid];
  H4u C;
  C.u = *(const uint2*)(qall + n * QREC + 768 + h * 64 + c * 4);
  const float4 a4 = *((const float4*)(aout + h * 64) + c);
  __syncthreads();
  float4 num = make_float4(0.f, 0.f, 0.f, 0.f);
  float4 den = make_float4(0.f, 0.f, 0.f, 0.f);
  for (int i = w; i < deg; i += 8) {
    int iB = i + 4;
    int vB = (iB < deg);  // wave-uniform
    uint4 rA = recs[i];
    uint4 rB = recs[vB ? iB : i];
    int sA, itA, sB, itB;
    unsigned i1A, q2A, q_A, i1B, q2B, q_B;
    dec_rec(rA, h, &sA, &itA, &i1A, &q2A, &q_A);
    dec_rec(rB, h, &sB, &itB, &i1B, &q2B, &q_B);
    H4u A0, B0, X0, Y0, Z0, A1, B1, X1, Y1, Z1;
    uint2 hr0, hr1;
    gather_edge(qall, U16, h, c, lane, sA, itA, i1A, q2A, q_A, &A0, &B0, &X0,
                &Y0, &Z0, &hr0);
    gather_edge(qall, U16, h, c, lane, sB, itB, i1B, q2B, q_B, &A1, &B1, &X1,
                &Y1, &Z1, &hr1);
    float v0 = tanh_dot(A0, B0, C, X0, Y0, Z0, a4);
    float v1 = tanh_dot(A1, B1, C, X1, Y1, Z1, a4);
    v0 = dpp_row_sum16(v0);
    v1 = dpp_row_sum16(v1);
    float ex0 = __expf(v0);
    float ex1 = vB ? __expf(v1) : 0.f;
    float4 hv0 = h4_to_f4(hr0);
    float4 hv1 = h4_to_f4(hr1);
    float e00 = __shfl(ex0, 0), e01 = __shfl(ex0, 16);
    float e02 = __shfl(ex0, 32), e03 = __shfl(ex0, 48);
    float e10 = __shfl(ex1, 0), e11 = __shfl(ex1, 16);
    float e12 = __shfl(ex1, 32), e13 = __shfl(ex1, 48);
    num.x += e00 * hv0.x + e10 * hv1.x;
    num.y += e01 * hv0.y + e11 * hv1.y;
    num.z += e02 * hv0.z + e12 * hv1.z;
    num.w += e03 * hv0.w + e13 * hv1.w;
    den.x += e00 + e10;
    den.y += e01 + e11;
    den.z += e02 + e12;
    den.w += e03 + e13;
  }
  sm_num[w][lane] = num;
  if (lane == 0) sm_den[w] = den;
  __syncthreads();
  if (tid < 64) {
    float4 n0 = sm_num[0][tid], n1 = sm_num[1][tid];
    float4 n2 = sm_num[2][tid], n3 = sm_num[3][tid];
    float4 d0 = sm_den[0], d1 = sm_den[1], d2 = sm_den[2], d3 = sm_den[3];
    float4 ns = make_float4(n0.x + n1.x + n2.x + n3.x, n0.y + n1.y + n2.y + n3.y,
                            n0.z + n1.z + n2.z + n3.z, n0.w + n1.w + n2.w + n3.w);
    float4 ds = make_float4(d0.x + d1.x + d2.x + d3.x, d0.y + d1.y + d2.y + d3.y,
                            d0.z + d1.z + d2.z + d3.z, d0.w + d1.w + d2.w + d3.w);
    float r = 0.f;
    if (deg > 0)
      r = 0.25f * (ns.x / ds.x + ns.y / ds.y + ns.z / ds.z + ns.w / ds.w);
    out[n * 64 + tid] = r;
  }
}

// ---------------------------------------------------------------------------
extern "C" void kernel_launch(void* const* d_in, const int* in_sizes, int n_in,
                              void* d_out, int out_size, void* d_ws,
                              size_t ws_size, hipStream_t stream) {
  const float* feat = (const float*)d_in[0];
  const float* loc = (const float*)d_in[1];
  const int* src = (const int*)d_in[2];
  const int* dst = (const int*)d_in[3];
  const int* inter = (const int*)d_in[4];
  const float* Wfc = (const float*)d_in[5];
  const float* emb = (const float*)d_in[6];
  const float* G = (const float*)d_in[7];
  const float* fc1 = (const float*)d_in[8];
  const float* fc2 = (const float*)d_in[9];
  const float* fc3 = (const float*)d_in[10];
  const float* fcc = (const float*)d_in[11];
  const float* aout = (const float*)d_in[12];
  const float* bnd = (const float*)d_in[13];
  float* out = (float*)d_out;

  __half* qall = (__half*)d_ws;           // N*1024 halfs (20.48 MB)
  __half* bigWT = qall + N_NODES * QREC;  // 1024*128 halfs
  __half* U16 = bigWT + 1024 * 128;       // 3*4*2048 halfs
  uint4* ebuf = (uint4*)(U16 + 3 * H * 2048);  // N*SLOTS uint4 (10.24 MB)
  int* cnt = (int*)(ebuf + N_NODES * SLOTS);   // N ints

  prep_kernel<<<44, 512, 0, stream>>>(fc1, fc2, fc3, fcc, Wfc, G, emb, bigWT,
                                      U16, cnt);
  gemm_edge_kernel<<<1253, 256, 0, stream>>>(feat, bigWT, qall, loc, src, dst,
                                             inter, bnd, cnt, ebuf);
  score_agg_kernel<<<N_NODES, 256, 0, stream>>>(cnt, ebuf, qall, U16, aout,
                                                out);
}